// Round 10
// baseline (261.142 us; speedup 1.0000x reference)
//
#include <hip/hip_runtime.h>
#include <stdint.h>

// WebAttention fused block for MI355X (gfx950).
// R10: split-K x2 on both GEMMs (blockIdx.z picks K-half; bf16 partials, adds
//      fused into rope_rms/v_trans and a small add_out). Attention unchanged (R9).
// WS map: 0-8 hbf (later o0), 8-20 Wcat (later o1 at 8-16), 20-28 Wot,
//         28-40 qkv0, 40-52 qkv1, 52-60 Qh, 60-62 Kh, 62-64 Vt, 64-72 Ao, 72 mb.

typedef unsigned short u16;
typedef unsigned short u16x4 __attribute__((ext_vector_type(4)));
typedef unsigned short u16x8 __attribute__((ext_vector_type(8)));
typedef __bf16 bf16x8 __attribute__((ext_vector_type(8)));
typedef float f32x4 __attribute__((ext_vector_type(4)));
typedef float f32x16 __attribute__((ext_vector_type(16)));

#define SLEN 2048
#define HIDDEN 2048
#define QKVN 3072   // 2048 Q + 512 K + 512 V
// Q pre-scale: 1/sqrt(64) * log2(e)  -> scores land in exp2 domain
#define QSCALE 0.18033688011112042f

__device__ __forceinline__ u16 f2bf(float x) {  // RNE, matches numpy/JAX
  uint32_t u = __float_as_uint(x);
  return (u16)((u + 0x7FFFu + ((u >> 16) & 1u)) >> 16);
}

__device__ __forceinline__ float bf2f(u16 x) {
  return __uint_as_float((uint32_t)x << 16);
}

__device__ __forceinline__ uint32_t cvtpk_bf16(float lo, float hi) {
  uint32_t r;
  asm("v_cvt_pk_bf16_f32 %0, %1, %2" : "=v"(r) : "v"(lo), "v"(hi));
  return r;
}

// Cross-half (lane ^ 32) reductions: {r[0],r[1]} = {self, partner} as a set.
__device__ __forceinline__ float xhalf_max(float x) {
  auto r = __builtin_amdgcn_permlane32_swap(__float_as_uint(x), __float_as_uint(x),
                                            false, false);
  return fmaxf(__uint_as_float(r[0]), __uint_as_float(r[1]));
}

__device__ __forceinline__ float xhalf_sum(float x) {
  auto r = __builtin_amdgcn_permlane32_swap(__float_as_uint(x), __float_as_uint(x),
                                            false, false);
  return __uint_as_float(r[0]) + __uint_as_float(r[1]);
}

__device__ __forceinline__ void gload_lds16(const void* g, void* l) {
  __builtin_amdgcn_global_load_lds(
      (const __attribute__((address_space(1))) void*)g,
      (__attribute__((address_space(3))) void*)l, 16, 0, 0);
}

// ---------------- prep kernels ----------------

__global__ __launch_bounds__(256) void cvt_f32_bf16(const float* __restrict__ in,
                                                    u16* __restrict__ out) {
  int idx = (blockIdx.x * 256 + threadIdx.x) * 4;
  float4 v = *(const float4*)(in + idx);
  u16x4 o;
  o[0] = f2bf(v.x); o[1] = f2bf(v.y); o[2] = f2bf(v.z); o[3] = f2bf(v.w);
  *(u16x4*)(out + idx) = o;
}

// in: f32 [K][ldin] row-major; out: bf16 [N][ldout] = transpose. grid (K/32, N/32).
__global__ __launch_bounds__(256) void transpose_w(const float* __restrict__ in, int ldin,
                                                   u16* __restrict__ out, int ldout) {
  __shared__ float tile[32][33];
  int k0 = blockIdx.x * 32, n0 = blockIdx.y * 32;
  int x = threadIdx.x & 31, y = threadIdx.x >> 5;  // y in 0..7
#pragma unroll
  for (int i = 0; i < 32; i += 8)
    tile[y + i][x] = in[(size_t)(k0 + y + i) * ldin + n0 + x];
  __syncthreads();
#pragma unroll
  for (int i = 0; i < 32; i += 8)
    out[(size_t)(n0 + y + i) * ldout + k0 + x] = f2bf(tile[x][y + i]);
}

// web mask [S][S] f32 (0 / -1e9) -> bitmask [S][64] u32 (bit=1 -> keep)
__global__ __launch_bounds__(256) void pack_mask(const float* __restrict__ m,
                                                 uint32_t* __restrict__ bits) {
  int w = blockIdx.x * 256 + threadIdx.x;  // 2048*64 words
  const float* p = m + (size_t)w * 32;
  uint32_t b = 0;
#pragma unroll
  for (int j = 0; j < 32; ++j) b |= (p[j] > -0.5f ? 1u : 0u) << j;
  bits[w] = b;
}

// ---- TN GEMM split-K x2: C[z][M][N] (bf16) = A[M][Kz] * B[N][Kz]^T ----
// 64x128 tile, BK=64, 4 waves (2x2), 32x64/wave, fragment-ordered LDS.
// blockIdx.z selects K-half; each half writes its own bf16 partial buffer.
__global__ __launch_bounds__(256) void gemm_tn_sk(const u16* __restrict__ A,
                                                  const u16* __restrict__ B,
                                                  u16* __restrict__ C0,
                                                  u16* __restrict__ C1,
                                                  int M, int N, int K) {
  __shared__ u16 As[64 * 64];    // 8 KB
  __shared__ u16 Bs[128 * 64];   // 16 KB
  const int tid = threadIdx.x;
  const int w = tid >> 6, l = tid & 63;
  const int bm = blockIdx.x, bn = blockIdx.y, z = blockIdx.z;
  const int wr = w >> 1, wc = w & 1;
  const int khalf = K >> 1;
  const int koff = z * khalf;
  u16* C = z ? C1 : C0;

  f32x4 acc[2][4] = {};

  int rowA[2], colA[2], ldsA[2];
#pragma unroll
  for (int g = 0; g < 2; ++g) {
    int c = g * 256 + w * 64 + l;
    rowA[g] = ((c >> 7) << 4) + (c & 15);
    colA[g] = ((c >> 4) & 7) * 8;
    ldsA[g] = (g * 256 + w * 64) * 8;
  }
  int rowB[4], colB[4], ldsB[4];
#pragma unroll
  for (int g = 0; g < 4; ++g) {
    int c = g * 256 + w * 64 + l;
    rowB[g] = ((c >> 7) << 4) + (c & 15);
    colB[g] = ((c >> 4) & 7) * 8;
    ldsB[g] = (g * 256 + w * 64) * 8;
  }
  const u16* Arow = A + (size_t)(bm * 64) * K;
  const u16* Brow = B + (size_t)(bn * 128) * K;

  for (int k0 = koff; k0 < koff + khalf; k0 += 64) {
    __syncthreads();
#pragma unroll
    for (int g = 0; g < 2; ++g)
      gload_lds16(Arow + (size_t)rowA[g] * K + k0 + colA[g], &As[ldsA[g]]);
#pragma unroll
    for (int g = 0; g < 4; ++g)
      gload_lds16(Brow + (size_t)rowB[g] * K + k0 + colB[g], &Bs[ldsB[g]]);
    asm volatile("s_waitcnt vmcnt(0)" ::: "memory");
    __syncthreads();
#pragma unroll
    for (int ks = 0; ks < 2; ++ks) {
      bf16x8 af[2], bfr[4];
#pragma unroll
      for (int mi = 0; mi < 2; ++mi)
        af[mi] = *(const bf16x8*)&As[(wr * 2 + mi) * 1024 + ks * 512 + l * 8];
#pragma unroll
      for (int ni = 0; ni < 4; ++ni)
        bfr[ni] = *(const bf16x8*)&Bs[(wc * 4 + ni) * 1024 + ks * 512 + l * 8];
#pragma unroll
      for (int mi = 0; mi < 2; ++mi)
#pragma unroll
        for (int ni = 0; ni < 4; ++ni)
          acc[mi][ni] = __builtin_amdgcn_mfma_f32_16x16x32_bf16(af[mi], bfr[ni],
                                                                acc[mi][ni], 0, 0, 0);
    }
  }
  const int cr = (l >> 4) * 4, cc = l & 15;
#pragma unroll
  for (int mi = 0; mi < 2; ++mi) {
    int row0 = bm * 64 + wr * 32 + mi * 16 + cr;
#pragma unroll
    for (int ni = 0; ni < 4; ++ni) {
      int col = bn * 128 + wc * 64 + ni * 16 + cc;
#pragma unroll
      for (int i = 0; i < 4; ++i)
        C[(size_t)(row0 + i) * N + col] = f2bf(acc[mi][ni][i]);
    }
  }
}

// ---- combine out-proj partials: out = bf2f(o0) + bf2f(o1) (fp32 out) ----
__global__ __launch_bounds__(256) void add_out(const u16* __restrict__ a,
                                               const u16* __restrict__ b,
                                               float* __restrict__ out) {
  int idx = (blockIdx.x * 256 + threadIdx.x) * 8;
  u16x8 va = *(const u16x8*)(a + idx);
  u16x8 vb = *(const u16x8*)(b + idx);
  float4 o0, o1;
  o0.x = bf2f(va[0]) + bf2f(vb[0]); o0.y = bf2f(va[1]) + bf2f(vb[1]);
  o0.z = bf2f(va[2]) + bf2f(vb[2]); o0.w = bf2f(va[3]) + bf2f(vb[3]);
  o1.x = bf2f(va[4]) + bf2f(vb[4]); o1.y = bf2f(va[5]) + bf2f(vb[5]);
  o1.z = bf2f(va[6]) + bf2f(vb[6]); o1.w = bf2f(va[7]) + bf2f(vb[7]);
  *(float4*)(out + idx) = o0;
  *(float4*)(out + idx + 4) = o1;
}

// ---------------- RoPE + RMSNorm epilogue (reads split-K partial pair) -------
__global__ __launch_bounds__(256) void rope_rms(const u16* __restrict__ qkv0,
                                                const u16* __restrict__ qkv1,
                                                const float* __restrict__ qw,
                                                const float* __restrict__ kw,
                                                u16* __restrict__ Qo,
                                                u16* __restrict__ Ko) {
  int s = blockIdx.x * 4 + (threadIdx.x >> 6);
  int hh = blockIdx.y;
  int d = threadIdx.x & 63;
  bool isq = hh < 32;
  int col = isq ? hh * 64 + d : 2048 + (hh - 32) * 64 + d;
  size_t idx = (size_t)s * QKVN + col;
  float x = bf2f(qkv0[idx]) + bf2f(qkv1[idx]);
  int i = d & 31;
  float inv_freq = exp2f(-(float)i * (13.287712379549449f / 32.0f));
  float ang = (float)s * inv_freq;
  float sn, cs;
  __sincosf(ang, &sn, &cs);
  float partner = __shfl_xor(x, 32, 64);
  float y = (d < 32) ? (x * cs - partner * sn) : (x * cs + partner * sn);
  float ss = y * y;
#pragma unroll
  for (int off = 32; off; off >>= 1) ss += __shfl_xor(ss, off, 64);
  float r = rsqrtf(ss * (1.0f / 64.0f) + 1e-6f);
  float o = y * r * (isq ? qw[d] : kw[d]);
  if (isq) Qo[((size_t)hh * SLEN + s) * 64 + d] = f2bf(o * QSCALE);
  else     Ko[((size_t)(hh - 32) * SLEN + s) * 64 + d] = f2bf(o);
}

// V slice of QKV partials -> V^T bf16 [8][64][S]
__global__ __launch_bounds__(256) void v_trans(const u16* __restrict__ qkv0,
                                               const u16* __restrict__ qkv1,
                                               u16* __restrict__ Vt) {
  __shared__ float tile[32][65];
  int kv = blockIdx.y;
  int s0 = blockIdx.x * 32;
  int tid = threadIdx.x;
  int d = tid & 63, r4 = tid >> 6;
#pragma unroll
  for (int i = 0; i < 32; i += 4) {
    size_t idx = (size_t)(s0 + i + r4) * QKVN + 2560 + kv * 64 + d;
    tile[i + r4][d] = bf2f(qkv0[idx]) + bf2f(qkv1[idx]);
  }
  __syncthreads();
  int dr = tid >> 2, sc = (tid & 3) * 8;
  u16x8 o;
#pragma unroll
  for (int j = 0; j < 8; ++j) o[j] = f2bf(tile[sc + j][dr]);
  *(u16x8*)(Vt + ((size_t)(kv * 64 + dr)) * SLEN + s0 + sc) = o;
}

// ---------------- flash attention, in-block split-K x4 (unchanged R9) --------
__global__ __launch_bounds__(256) void attn_fused(const u16* __restrict__ Q,
                                                  const u16* __restrict__ Kh,
                                                  const u16* __restrict__ Vt,
                                                  const uint32_t* __restrict__ mbits,
                                                  u16* __restrict__ Aout) {
  __shared__ float accS[4 * 32 * 64];  // 32 KB
  __shared__ float2 mlS[4 * 32];       // 1 KB
  const int w = threadIdx.x >> 6, l = threadIdx.x & 63;
  const int h = blockIdx.x;
  const int qt = 63 - blockIdx.y;      // longest blocks dispatched first
  const int q0 = qt * 32;
  const int hkv = h >> 2;
  const bool web = (h >= 16);
  const int l31 = l & 31, hi = l >> 5;
  const int qrel = l31 - 4 * hi;  // diag-block causal: keep iff ki <= qrel
  const int nkb = qt + 1;

  const u16* Qp = Q + ((size_t)h * SLEN + q0 + l31) * 64 + hi * 8;
  bf16x8 qf0 = *(const bf16x8*)(Qp);
  bf16x8 qf1 = *(const bf16x8*)(Qp + 16);
  bf16x8 qf2 = *(const bf16x8*)(Qp + 32);
  bf16x8 qf3 = *(const bf16x8*)(Qp + 48);

  const u16* Kp = Kh + ((size_t)hkv * SLEN + l31) * 64 + hi * 8;
  const u16* Vp = Vt + ((size_t)hkv * 64 + l31) * SLEN + hi * 8;
  const uint32_t* mrow = mbits + (size_t)(q0 + l31) * 64;

  f32x16 acc0 = {}, acc1 = {};   // O^T[d][q]
  float m = -1e30f, ll = 0.f;

  if (w < nkb) {
    const u16* kp = Kp + (size_t)w * 64 * 32;
    bf16x8 kc0 = *(const bf16x8*)(kp);
    bf16x8 kc1 = *(const bf16x8*)(kp + 16);
    bf16x8 kc2 = *(const bf16x8*)(kp + 32);
    bf16x8 kc3 = *(const bf16x8*)(kp + 48);
    const u16* vp0 = Vp + w * 32;
    bf16x8 vc00 = *(const bf16x8*)(vp0);
    bf16x8 vc01 = *(const bf16x8*)(vp0 + 16);
    bf16x8 vc10 = *(const bf16x8*)(vp0 + 32 * SLEN);
    bf16x8 vc11 = *(const bf16x8*)(vp0 + 32 * SLEN + 16);
    uint32_t wcur = web ? mrow[w] : 0u;

    for (int kb = w; kb < nkb; kb += 4) {
      bf16x8 kn0, kn1, kn2, kn3, vn00, vn01, vn10, vn11;
      uint32_t wnext = 0u;
      if (kb + 4 < nkb) {
        const u16* knp = Kp + (size_t)(kb + 4) * 64 * 32;
        kn0 = *(const bf16x8*)(knp);
        kn1 = *(const bf16x8*)(knp + 16);
        kn2 = *(const bf16x8*)(knp + 32);
        kn3 = *(const bf16x8*)(knp + 48);
        const u16* vnp = Vp + (kb + 4) * 32;
        vn00 = *(const bf16x8*)(vnp);
        vn01 = *(const bf16x8*)(vnp + 16);
        vn10 = *(const bf16x8*)(vnp + 32 * SLEN);
        vn11 = *(const bf16x8*)(vnp + 32 * SLEN + 16);
        if (web) wnext = mrow[kb + 4];
      }
      f32x16 s = {};
      s = __builtin_amdgcn_mfma_f32_32x32x16_bf16(kc0, qf0, s, 0, 0, 0);
      s = __builtin_amdgcn_mfma_f32_32x32x16_bf16(kc1, qf1, s, 0, 0, 0);
      s = __builtin_amdgcn_mfma_f32_32x32x16_bf16(kc2, qf2, s, 0, 0, 0);
      s = __builtin_amdgcn_mfma_f32_32x32x16_bf16(kc3, qf3, s, 0, 0, 0);
      if (web) {
        uint32_t word = wcur >> (hi * 4);
        if (kb == qt) {
#pragma unroll
          for (int r = 0; r < 16; ++r) {
            const int ki = (r & 3) + 8 * (r >> 2);
            bool keep = ((word >> ki) & 1u) && (ki <= qrel);
            s[r] = keep ? s[r] : -1e9f;
          }
        } else {
#pragma unroll
          for (int r = 0; r < 16; ++r) {
            const int ki = (r & 3) + 8 * (r >> 2);
            s[r] = ((word >> ki) & 1u) ? s[r] : -1e9f;
          }
        }
      } else if (kb == qt) {
#pragma unroll
        for (int r = 0; r < 16; ++r) {
          const int ki = (r & 3) + 8 * (r >> 2);
          s[r] = (ki <= qrel) ? s[r] : -1e9f;
        }
      }
      float pm = s[0];
#pragma unroll
      for (int r = 1; r < 16; ++r) pm = fmaxf(pm, s[r]);
      pm = xhalf_max(pm);
      if (__any(pm > m + 8.0f)) {           // defer-max, log2 units
        float nm = fmaxf(m, pm);
        float al = exp2f(m - nm);
#pragma unroll
        for (int r = 0; r < 16; ++r) { acc0[r] *= al; acc1[r] *= al; }
        ll *= al;
        m = nm;
      }
      f32x16 p;
#pragma unroll
      for (int r = 0; r < 16; ++r) p[r] = exp2f(s[r] - m);
      float rs = 0.f;
#pragma unroll
      for (int r = 0; r < 16; ++r) rs += p[r];
      ll += xhalf_sum(rs);
      uint32_t a0 = cvtpk_bf16(p[0], p[1]),   b0 = cvtpk_bf16(p[2], p[3]);
      uint32_t c0 = cvtpk_bf16(p[4], p[5]),   d0 = cvtpk_bf16(p[6], p[7]);
      uint32_t a1 = cvtpk_bf16(p[8], p[9]),   b1 = cvtpk_bf16(p[10], p[11]);
      uint32_t c1 = cvtpk_bf16(p[12], p[13]), d1 = cvtpk_bf16(p[14], p[15]);
      auto r0 = __builtin_amdgcn_permlane32_swap(a0, c0, false, false);
      auto r1 = __builtin_amdgcn_permlane32_swap(b0, d0, false, false);
      auto r2 = __builtin_amdgcn_permlane32_swap(a1, c1, false, false);
      auto r3 = __builtin_amdgcn_permlane32_swap(b1, d1, false, false);
      union { uint32_t w[4]; bf16x8 v; } pf0u, pf1u;
      pf0u.w[0] = r0[0]; pf0u.w[1] = r1[0]; pf0u.w[2] = r0[1]; pf0u.w[3] = r1[1];
      pf1u.w[0] = r2[0]; pf1u.w[1] = r3[0]; pf1u.w[2] = r2[1]; pf1u.w[3] = r3[1];
      acc0 = __builtin_amdgcn_mfma_f32_32x32x16_bf16(vc00, pf0u.v, acc0, 0, 0, 0);
      acc0 = __builtin_amdgcn_mfma_f32_32x32x16_bf16(vc01, pf1u.v, acc0, 0, 0, 0);
      acc1 = __builtin_amdgcn_mfma_f32_32x32x16_bf16(vc10, pf0u.v, acc1, 0, 0, 0);
      acc1 = __builtin_amdgcn_mfma_f32_32x32x16_bf16(vc11, pf1u.v, acc1, 0, 0, 0);
      kc0 = kn0; kc1 = kn1; kc2 = kn2; kc3 = kn3;
      vc00 = vn00; vc01 = vn01; vc10 = vn10; vc11 = vn11;
      wcur = wnext;
    }
  }
  // ---- stash per-wave state in LDS (raw acc + m,l) ----
  if (hi == 0) mlS[w * 32 + l31] = make_float2(m, ll);
  float* wbase = accS + w * 2048 + (l31 << 6);
  const int sw = (l31 & 15) << 2;  // swizzle: d ^= sw
#pragma unroll
  for (int t = 0; t < 4; ++t) {
    int dA = (8 * t + 4 * hi) ^ sw;
    int dB = (32 + 8 * t + 4 * hi) ^ sw;
    float4 v0 = {acc0[4 * t], acc0[4 * t + 1], acc0[4 * t + 2], acc0[4 * t + 3]};
    float4 v1 = {acc1[4 * t], acc1[4 * t + 1], acc1[4 * t + 2], acc1[4 * t + 3]};
    *(float4*)(wbase + dA) = v0;
    *(float4*)(wbase + dB) = v1;
  }
  __syncthreads();
  // ---- combine: thread -> (q = tid&31, d = (tid>>5)*8) ----
  const int q = threadIdx.x & 31;
  const int dd = (threadIdx.x >> 5) * 8;
  float2 ml0 = mlS[q], ml1 = mlS[32 + q], ml2 = mlS[64 + q], ml3 = mlS[96 + q];
  float M = fmaxf(fmaxf(ml0.x, ml1.x), fmaxf(ml2.x, ml3.x));
  float w0 = exp2f(ml0.x - M), w1 = exp2f(ml1.x - M);
  float w2 = exp2f(ml2.x - M), w3 = exp2f(ml3.x - M);
  float L = ml0.y * w0 + ml1.y * w1 + ml2.y * w2 + ml3.y * w3;
  const int offA = (q << 6) + (dd ^ ((q & 15) << 2));
  const int offB = offA ^ 4;
  float o[8];
  {
    float4 xa = *(float4*)(accS + offA);
    float4 xb = *(float4*)(accS + offB);
    o[0] = w0 * xa.x; o[1] = w0 * xa.y; o[2] = w0 * xa.z; o[3] = w0 * xa.w;
    o[4] = w0 * xb.x; o[5] = w0 * xb.y; o[6] = w0 * xb.z; o[7] = w0 * xb.w;
  }
  {
    float4 xa = *(float4*)(accS + 2048 + offA);
    float4 xb = *(float4*)(accS + 2048 + offB);
    o[0] += w1 * xa.x; o[1] += w1 * xa.y; o[2] += w1 * xa.z; o[3] += w1 * xa.w;
    o[4] += w1 * xb.x; o[5] += w1 * xb.y; o[6] += w1 * xb.z; o[7] += w1 * xb.w;
  }
  {
    float4 xa = *(float4*)(accS + 4096 + offA);
    float4 xb = *(float4*)(accS + 4096 + offB);
    o[0] += w2 * xa.x; o[1] += w2 * xa.y; o[2] += w2 * xa.z; o[3] += w2 * xa.w;
    o[4] += w2 * xb.x; o[5] += w2 * xb.y; o[6] += w2 * xb.z; o[7] += w2 * xb.w;
  }
  {
    float4 xa = *(float4*)(accS + 6144 + offA);
    float4 xb = *(float4*)(accS + 6144 + offB);
    o[0] += w3 * xa.x; o[1] += w3 * xa.y; o[2] += w3 * xa.z; o[3] += w3 * xa.w;
    o[4] += w3 * xb.x; o[5] += w3 * xb.y; o[6] += w3 * xb.z; o[7] += w3 * xb.w;
  }
  const float invL = 1.0f / L;
  uint4 pk;
  pk.x = cvtpk_bf16(o[0] * invL, o[1] * invL);
  pk.y = cvtpk_bf16(o[2] * invL, o[3] * invL);
  pk.z = cvtpk_bf16(o[4] * invL, o[5] * invL);
  pk.w = cvtpk_bf16(o[6] * invL, o[7] * invL);
  *(uint4*)(Aout + (size_t)(q0 + q) * HIDDEN + h * 64 + dd) = pk;
}

// ---------------- launch ----------------

extern "C" void kernel_launch(void* const* d_in, const int* in_sizes, int n_in,
                              void* d_out, int out_size, void* d_ws, size_t ws_size,
                              hipStream_t stream) {
  const float* hidden  = (const float*)d_in[0];
  const float* webmask = (const float*)d_in[3];
  const float* Wq = (const float*)d_in[4];
  const float* Wk = (const float*)d_in[5];
  const float* Wv = (const float*)d_in[6];
  const float* Wo = (const float*)d_in[7];
  const float* qlnw = (const float*)d_in[8];
  const float* klnw = (const float*)d_in[9];
  float* out = (float*)d_out;

  char* ws = (char*)d_ws;
  u16*      hbf  = (u16*)(ws);                         // 8 MB  hidden bf16 (dead after QKV gemm)
  u16*      Wcat = (u16*)(ws + (8u << 20));            // 12 MB QKV W^T (dead after QKV gemm)
  u16*      Wot  = (u16*)(ws + (20u << 20));           // 8 MB  Wo^T
  u16*      qkv0 = (u16*)(ws + (28u << 20));           // 12 MB QKV partial z=0 (bf16)
  u16*      qkv1 = (u16*)(ws + (40u << 20));           // 12 MB QKV partial z=1
  u16*      Qh   = (u16*)(ws + (52u << 20));           // 8 MB  Q' (pre-scaled)
  u16*      Kh   = (u16*)(ws + (60u << 20));           // 2 MB  K'
  u16*      Vt   = (u16*)(ws + (62u << 20));           // 2 MB  V^T
  u16*      Ao   = (u16*)(ws + (64u << 20));           // 8 MB  attn out bf16
  uint32_t* mb   = (uint32_t*)(ws + (72u << 20));      // 0.5 MB web mask bits
  // out-proj partials overlay hbf/Wcat (dead after QKV gemm):
  u16*      o0   = (u16*)(ws);                         // 8 MB
  u16*      o1   = (u16*)(ws + (8u << 20));            // 8 MB

  cvt_f32_bf16<<<4096, 256, 0, stream>>>(hidden, hbf);
  transpose_w<<<dim3(64, 64), 256, 0, stream>>>(Wq, 2048, Wcat, 2048);
  transpose_w<<<dim3(64, 16), 256, 0, stream>>>(Wk, 512, Wcat + (size_t)2048 * 2048, 2048);
  transpose_w<<<dim3(64, 16), 256, 0, stream>>>(Wv, 512, Wcat + (size_t)2560 * 2048, 2048);
  transpose_w<<<dim3(64, 64), 256, 0, stream>>>(Wo, 2048, Wot, 2048);
  pack_mask<<<512, 256, 0, stream>>>(webmask, mb);

  gemm_tn_sk<<<dim3(32, 24, 2), 256, 0, stream>>>(hbf, Wcat, qkv0, qkv1,
                                                  SLEN, QKVN, HIDDEN);
  rope_rms<<<dim3(512, 40), 256, 0, stream>>>(qkv0, qkv1, qlnw, klnw, Qh, Kh);
  v_trans<<<dim3(64, 8), 256, 0, stream>>>(qkv0, qkv1, Vt);
  attn_fused<<<dim3(32, 64), 256, 0, stream>>>(Qh, Kh, Vt, mb, Ao);
  gemm_tn_sk<<<dim3(32, 16, 2), 256, 0, stream>>>(Ao, Wot, o0, o1,
                                                  SLEN, HIDDEN, HIDDEN);
  add_out<<<2048, 256, 0, stream>>>(o0, o1, out);
}

// Round 11
// 249.198 us; speedup vs baseline: 1.0479x; 1.0479x over previous
//
#include <hip/hip_runtime.h>
#include <stdint.h>

// WebAttention fused block for MI355X (gfx950).
// R11: R9 structure + XCD-chunked block remaps (xcd = linear%8 heuristic):
//   - gemm_tn: XCD owns 4 bm rows (A chunk 1MB L2-resident), bn outer/bm inner
//     so each B panel is consumed back-to-back (L3 traffic 576->~104 MB QKV).
//   - attn_fused: XCD owns 4 heads = ONE kv head -> K/V (1MB) L2-resident.
// Split-K on GEMMs reverted (R10 showed GEMMs are cache-BW bound, not occupancy).

typedef unsigned short u16;
typedef unsigned short u16x4 __attribute__((ext_vector_type(4)));
typedef unsigned short u16x8 __attribute__((ext_vector_type(8)));
typedef __bf16 bf16x8 __attribute__((ext_vector_type(8)));
typedef float f32x4 __attribute__((ext_vector_type(4)));
typedef float f32x16 __attribute__((ext_vector_type(16)));

#define SLEN 2048
#define HIDDEN 2048
#define QKVN 3072   // 2048 Q + 512 K + 512 V
// Q pre-scale: 1/sqrt(64) * log2(e)  -> scores land in exp2 domain
#define QSCALE 0.18033688011112042f

__device__ __forceinline__ u16 f2bf(float x) {  // RNE, matches numpy/JAX
  uint32_t u = __float_as_uint(x);
  return (u16)((u + 0x7FFFu + ((u >> 16) & 1u)) >> 16);
}

__device__ __forceinline__ uint32_t cvtpk_bf16(float lo, float hi) {
  uint32_t r;
  asm("v_cvt_pk_bf16_f32 %0, %1, %2" : "=v"(r) : "v"(lo), "v"(hi));
  return r;
}

// Cross-half (lane ^ 32) reductions: {r[0],r[1]} = {self, partner} as a set.
__device__ __forceinline__ float xhalf_max(float x) {
  auto r = __builtin_amdgcn_permlane32_swap(__float_as_uint(x), __float_as_uint(x),
                                            false, false);
  return fmaxf(__uint_as_float(r[0]), __uint_as_float(r[1]));
}

__device__ __forceinline__ float xhalf_sum(float x) {
  auto r = __builtin_amdgcn_permlane32_swap(__float_as_uint(x), __float_as_uint(x),
                                            false, false);
  return __uint_as_float(r[0]) + __uint_as_float(r[1]);
}

__device__ __forceinline__ void gload_lds16(const void* g, void* l) {
  __builtin_amdgcn_global_load_lds(
      (const __attribute__((address_space(1))) void*)g,
      (__attribute__((address_space(3))) void*)l, 16, 0, 0);
}

// ---------------- prep kernels ----------------

__global__ __launch_bounds__(256) void cvt_f32_bf16(const float* __restrict__ in,
                                                    u16* __restrict__ out) {
  int idx = (blockIdx.x * 256 + threadIdx.x) * 4;
  float4 v = *(const float4*)(in + idx);
  u16x4 o;
  o[0] = f2bf(v.x); o[1] = f2bf(v.y); o[2] = f2bf(v.z); o[3] = f2bf(v.w);
  *(u16x4*)(out + idx) = o;
}

// in: f32 [K][ldin] row-major; out: bf16 [N][ldout] = transpose. grid (K/32, N/32).
__global__ __launch_bounds__(256) void transpose_w(const float* __restrict__ in, int ldin,
                                                   u16* __restrict__ out, int ldout) {
  __shared__ float tile[32][33];
  int k0 = blockIdx.x * 32, n0 = blockIdx.y * 32;
  int x = threadIdx.x & 31, y = threadIdx.x >> 5;  // y in 0..7
#pragma unroll
  for (int i = 0; i < 32; i += 8)
    tile[y + i][x] = in[(size_t)(k0 + y + i) * ldin + n0 + x];
  __syncthreads();
#pragma unroll
  for (int i = 0; i < 32; i += 8)
    out[(size_t)(n0 + y + i) * ldout + k0 + x] = f2bf(tile[x][y + i]);
}

// web mask [S][S] f32 (0 / -1e9) -> bitmask [S][64] u32 (bit=1 -> keep)
__global__ __launch_bounds__(256) void pack_mask(const float* __restrict__ m,
                                                 uint32_t* __restrict__ bits) {
  int w = blockIdx.x * 256 + threadIdx.x;  // 2048*64 words
  const float* p = m + (size_t)w * 32;
  uint32_t b = 0;
#pragma unroll
  for (int j = 0; j < 32; ++j) b |= (p[j] > -0.5f ? 1u : 0u) << j;
  bits[w] = b;
}

// ---------------- TN GEMM: C[M][N] = A[M][K] * B[N][K]^T (bf16 in, fp32 out) --------
// 64x128 tile, BK=64, 4 waves (2x2), 32x64/wave, fragment-ordered LDS.
// 1-D grid + XCD-chunk remap: xcd = lin&7 owns bm in [4*xcd, 4*xcd+4)
// (A chunk 1MB stays in that XCD's L2); bn advances slowly (pos>>2) with bm
// inner (pos&3) so each B panel is consumed by its 4 blocks back-to-back.
// Requires M == 2048 (nbm=32 -> 4 rows/XCD).
__global__ __launch_bounds__(256) void gemm_tn(const u16* __restrict__ A,
                                               const u16* __restrict__ B,
                                               float* __restrict__ C,
                                               int M, int N, int K) {
  __shared__ u16 As[64 * 64];    // 8 KB
  __shared__ u16 Bs[128 * 64];   // 16 KB
  const int tid = threadIdx.x;
  const int w = tid >> 6, l = tid & 63;
  const int lin = blockIdx.x;
  const int xcd = lin & 7, pos = lin >> 3;
  const int bm = xcd * 4 + (pos & 3);
  const int bn = pos >> 2;
  const int wr = w >> 1, wc = w & 1;

  f32x4 acc[2][4] = {};

  int rowA[2], colA[2], ldsA[2];
#pragma unroll
  for (int g = 0; g < 2; ++g) {
    int c = g * 256 + w * 64 + l;
    rowA[g] = ((c >> 7) << 4) + (c & 15);
    colA[g] = ((c >> 4) & 7) * 8;
    ldsA[g] = (g * 256 + w * 64) * 8;
  }
  int rowB[4], colB[4], ldsB[4];
#pragma unroll
  for (int g = 0; g < 4; ++g) {
    int c = g * 256 + w * 64 + l;
    rowB[g] = ((c >> 7) << 4) + (c & 15);
    colB[g] = ((c >> 4) & 7) * 8;
    ldsB[g] = (g * 256 + w * 64) * 8;
  }
  const u16* Arow = A + (size_t)(bm * 64) * K;
  const u16* Brow = B + (size_t)(bn * 128) * K;

  for (int k0 = 0; k0 < K; k0 += 64) {
    __syncthreads();
#pragma unroll
    for (int g = 0; g < 2; ++g)
      gload_lds16(Arow + (size_t)rowA[g] * K + k0 + colA[g], &As[ldsA[g]]);
#pragma unroll
    for (int g = 0; g < 4; ++g)
      gload_lds16(Brow + (size_t)rowB[g] * K + k0 + colB[g], &Bs[ldsB[g]]);
    asm volatile("s_waitcnt vmcnt(0)" ::: "memory");
    __syncthreads();
#pragma unroll
    for (int ks = 0; ks < 2; ++ks) {
      bf16x8 af[2], bfr[4];
#pragma unroll
      for (int mi = 0; mi < 2; ++mi)
        af[mi] = *(const bf16x8*)&As[(wr * 2 + mi) * 1024 + ks * 512 + l * 8];
#pragma unroll
      for (int ni = 0; ni < 4; ++ni)
        bfr[ni] = *(const bf16x8*)&Bs[(wc * 4 + ni) * 1024 + ks * 512 + l * 8];
#pragma unroll
      for (int mi = 0; mi < 2; ++mi)
#pragma unroll
        for (int ni = 0; ni < 4; ++ni)
          acc[mi][ni] = __builtin_amdgcn_mfma_f32_16x16x32_bf16(af[mi], bfr[ni],
                                                                acc[mi][ni], 0, 0, 0);
    }
  }
  const int cr = (l >> 4) * 4, cc = l & 15;
#pragma unroll
  for (int mi = 0; mi < 2; ++mi) {
    int row0 = bm * 64 + wr * 32 + mi * 16 + cr;
#pragma unroll
    for (int ni = 0; ni < 4; ++ni) {
      int col = bn * 128 + wc * 64 + ni * 16 + cc;
#pragma unroll
      for (int i = 0; i < 4; ++i)
        C[(size_t)(row0 + i) * N + col] = acc[mi][ni][i];
    }
  }
}

// ---------------- RoPE + RMSNorm epilogue ----------------
__global__ __launch_bounds__(256) void rope_rms(const float* __restrict__ qkv,
                                                const float* __restrict__ qw,
                                                const float* __restrict__ kw,
                                                u16* __restrict__ Qo,
                                                u16* __restrict__ Ko) {
  int s = blockIdx.x * 4 + (threadIdx.x >> 6);
  int hh = blockIdx.y;
  int d = threadIdx.x & 63;
  bool isq = hh < 32;
  int col = isq ? hh * 64 + d : 2048 + (hh - 32) * 64 + d;
  float x = qkv[(size_t)s * QKVN + col];
  int i = d & 31;
  float inv_freq = exp2f(-(float)i * (13.287712379549449f / 32.0f));
  float ang = (float)s * inv_freq;
  float sn, cs;
  __sincosf(ang, &sn, &cs);
  float partner = __shfl_xor(x, 32, 64);
  float y = (d < 32) ? (x * cs - partner * sn) : (x * cs + partner * sn);
  float ss = y * y;
#pragma unroll
  for (int off = 32; off; off >>= 1) ss += __shfl_xor(ss, off, 64);
  float r = rsqrtf(ss * (1.0f / 64.0f) + 1e-6f);
  float o = y * r * (isq ? qw[d] : kw[d]);
  if (isq) Qo[((size_t)hh * SLEN + s) * 64 + d] = f2bf(o * QSCALE);
  else     Ko[((size_t)(hh - 32) * SLEN + s) * 64 + d] = f2bf(o);
}

// V slice of QKV -> V^T bf16 [8][64][S]
__global__ __launch_bounds__(256) void v_trans(const float* __restrict__ qkv,
                                               u16* __restrict__ Vt) {
  __shared__ float tile[32][65];
  int kv = blockIdx.y;
  int s0 = blockIdx.x * 32;
  int tid = threadIdx.x;
  int d = tid & 63, r4 = tid >> 6;
#pragma unroll
  for (int i = 0; i < 32; i += 4)
    tile[i + r4][d] = qkv[(size_t)(s0 + i + r4) * QKVN + 2560 + kv * 64 + d];
  __syncthreads();
  int dr = tid >> 2, sc = (tid & 3) * 8;
  u16x8 o;
#pragma unroll
  for (int j = 0; j < 8; ++j) o[j] = f2bf(tile[sc + j][dr]);
  *(u16x8*)(Vt + ((size_t)(kv * 64 + dr)) * SLEN + s0 + sc) = o;
}

// ---------------- flash attention, in-block split-K x4 ----------------
// 1-D grid 2048 + XCD remap: xcd = lin&7 owns heads [4*xcd, 4*xcd+4) -> ONE
// kv head per XCD -> K+V (1 MB) stays L2-resident. qt = 63-(pos>>2): longest
// first. Wave w takes kb = w, w+4, ...; LDS combine; Ao written directly.
__global__ __launch_bounds__(256) void attn_fused(const u16* __restrict__ Q,
                                                  const u16* __restrict__ Kh,
                                                  const u16* __restrict__ Vt,
                                                  const uint32_t* __restrict__ mbits,
                                                  u16* __restrict__ Aout) {
  __shared__ float accS[4 * 32 * 64];  // 32 KB
  __shared__ float2 mlS[4 * 32];       // 1 KB
  const int w = threadIdx.x >> 6, l = threadIdx.x & 63;
  const int lin = blockIdx.x;
  const int xcd = lin & 7, pos = lin >> 3;
  const int h = xcd * 4 + (pos & 3);   // 4 heads/XCD = one kv head
  const int qt = 63 - (pos >> 2);      // longest blocks dispatched first
  const int q0 = qt * 32;
  const int hkv = h >> 2;
  const bool web = (h >= 16);
  const int l31 = l & 31, hi = l >> 5;
  const int qrel = l31 - 4 * hi;  // diag-block causal: keep iff ki <= qrel
  const int nkb = qt + 1;

  const u16* Qp = Q + ((size_t)h * SLEN + q0 + l31) * 64 + hi * 8;
  bf16x8 qf0 = *(const bf16x8*)(Qp);
  bf16x8 qf1 = *(const bf16x8*)(Qp + 16);
  bf16x8 qf2 = *(const bf16x8*)(Qp + 32);
  bf16x8 qf3 = *(const bf16x8*)(Qp + 48);

  const u16* Kp = Kh + ((size_t)hkv * SLEN + l31) * 64 + hi * 8;
  const u16* Vp = Vt + ((size_t)hkv * 64 + l31) * SLEN + hi * 8;
  const uint32_t* mrow = mbits + (size_t)(q0 + l31) * 64;

  f32x16 acc0 = {}, acc1 = {};   // O^T[d][q]
  float m = -1e30f, ll = 0.f;

  if (w < nkb) {
    const u16* kp = Kp + (size_t)w * 64 * 32;
    bf16x8 kc0 = *(const bf16x8*)(kp);
    bf16x8 kc1 = *(const bf16x8*)(kp + 16);
    bf16x8 kc2 = *(const bf16x8*)(kp + 32);
    bf16x8 kc3 = *(const bf16x8*)(kp + 48);
    const u16* vp0 = Vp + w * 32;
    bf16x8 vc00 = *(const bf16x8*)(vp0);
    bf16x8 vc01 = *(const bf16x8*)(vp0 + 16);
    bf16x8 vc10 = *(const bf16x8*)(vp0 + 32 * SLEN);
    bf16x8 vc11 = *(const bf16x8*)(vp0 + 32 * SLEN + 16);
    uint32_t wcur = web ? mrow[w] : 0u;

    for (int kb = w; kb < nkb; kb += 4) {
      bf16x8 kn0, kn1, kn2, kn3, vn00, vn01, vn10, vn11;
      uint32_t wnext = 0u;
      if (kb + 4 < nkb) {
        const u16* knp = Kp + (size_t)(kb + 4) * 64 * 32;
        kn0 = *(const bf16x8*)(knp);
        kn1 = *(const bf16x8*)(knp + 16);
        kn2 = *(const bf16x8*)(knp + 32);
        kn3 = *(const bf16x8*)(knp + 48);
        const u16* vnp = Vp + (kb + 4) * 32;
        vn00 = *(const bf16x8*)(vnp);
        vn01 = *(const bf16x8*)(vnp + 16);
        vn10 = *(const bf16x8*)(vnp + 32 * SLEN);
        vn11 = *(const bf16x8*)(vnp + 32 * SLEN + 16);
        if (web) wnext = mrow[kb + 4];
      }
      f32x16 s = {};
      s = __builtin_amdgcn_mfma_f32_32x32x16_bf16(kc0, qf0, s, 0, 0, 0);
      s = __builtin_amdgcn_mfma_f32_32x32x16_bf16(kc1, qf1, s, 0, 0, 0);
      s = __builtin_amdgcn_mfma_f32_32x32x16_bf16(kc2, qf2, s, 0, 0, 0);
      s = __builtin_amdgcn_mfma_f32_32x32x16_bf16(kc3, qf3, s, 0, 0, 0);
      if (web) {
        uint32_t word = wcur >> (hi * 4);
        if (kb == qt) {
#pragma unroll
          for (int r = 0; r < 16; ++r) {
            const int ki = (r & 3) + 8 * (r >> 2);
            bool keep = ((word >> ki) & 1u) && (ki <= qrel);
            s[r] = keep ? s[r] : -1e9f;
          }
        } else {
#pragma unroll
          for (int r = 0; r < 16; ++r) {
            const int ki = (r & 3) + 8 * (r >> 2);
            s[r] = ((word >> ki) & 1u) ? s[r] : -1e9f;
          }
        }
      } else if (kb == qt) {
#pragma unroll
        for (int r = 0; r < 16; ++r) {
          const int ki = (r & 3) + 8 * (r >> 2);
          s[r] = (ki <= qrel) ? s[r] : -1e9f;
        }
      }
      float pm = s[0];
#pragma unroll
      for (int r = 1; r < 16; ++r) pm = fmaxf(pm, s[r]);
      pm = xhalf_max(pm);
      if (__any(pm > m + 8.0f)) {           // defer-max, log2 units
        float nm = fmaxf(m, pm);
        float al = exp2f(m - nm);
#pragma unroll
        for (int r = 0; r < 16; ++r) { acc0[r] *= al; acc1[r] *= al; }
        ll *= al;
        m = nm;
      }
      f32x16 p;
#pragma unroll
      for (int r = 0; r < 16; ++r) p[r] = exp2f(s[r] - m);
      float rs = 0.f;
#pragma unroll
      for (int r = 0; r < 16; ++r) rs += p[r];
      ll += xhalf_sum(rs);
      uint32_t a0 = cvtpk_bf16(p[0], p[1]),   b0 = cvtpk_bf16(p[2], p[3]);
      uint32_t c0 = cvtpk_bf16(p[4], p[5]),   d0 = cvtpk_bf16(p[6], p[7]);
      uint32_t a1 = cvtpk_bf16(p[8], p[9]),   b1 = cvtpk_bf16(p[10], p[11]);
      uint32_t c1 = cvtpk_bf16(p[12], p[13]), d1 = cvtpk_bf16(p[14], p[15]);
      auto r0 = __builtin_amdgcn_permlane32_swap(a0, c0, false, false);
      auto r1 = __builtin_amdgcn_permlane32_swap(b0, d0, false, false);
      auto r2 = __builtin_amdgcn_permlane32_swap(a1, c1, false, false);
      auto r3 = __builtin_amdgcn_permlane32_swap(b1, d1, false, false);
      union { uint32_t w[4]; bf16x8 v; } pf0u, pf1u;
      pf0u.w[0] = r0[0]; pf0u.w[1] = r1[0]; pf0u.w[2] = r0[1]; pf0u.w[3] = r1[1];
      pf1u.w[0] = r2[0]; pf1u.w[1] = r3[0]; pf1u.w[2] = r2[1]; pf1u.w[3] = r3[1];
      acc0 = __builtin_amdgcn_mfma_f32_32x32x16_bf16(vc00, pf0u.v, acc0, 0, 0, 0);
      acc0 = __builtin_amdgcn_mfma_f32_32x32x16_bf16(vc01, pf1u.v, acc0, 0, 0, 0);
      acc1 = __builtin_amdgcn_mfma_f32_32x32x16_bf16(vc10, pf0u.v, acc1, 0, 0, 0);
      acc1 = __builtin_amdgcn_mfma_f32_32x32x16_bf16(vc11, pf1u.v, acc1, 0, 0, 0);
      kc0 = kn0; kc1 = kn1; kc2 = kn2; kc3 = kn3;
      vc00 = vn00; vc01 = vn01; vc10 = vn10; vc11 = vn11;
      wcur = wnext;
    }
  }
  // ---- stash per-wave state in LDS (raw acc + m,l) ----
  if (hi == 0) mlS[w * 32 + l31] = make_float2(m, ll);
  float* wbase = accS + w * 2048 + (l31 << 6);
  const int sw = (l31 & 15) << 2;  // swizzle: d ^= sw
#pragma unroll
  for (int t = 0; t < 4; ++t) {
    int dA = (8 * t + 4 * hi) ^ sw;
    int dB = (32 + 8 * t + 4 * hi) ^ sw;
    float4 v0 = {acc0[4 * t], acc0[4 * t + 1], acc0[4 * t + 2], acc0[4 * t + 3]};
    float4 v1 = {acc1[4 * t], acc1[4 * t + 1], acc1[4 * t + 2], acc1[4 * t + 3]};
    *(float4*)(wbase + dA) = v0;
    *(float4*)(wbase + dB) = v1;
  }
  __syncthreads();
  // ---- combine: thread -> (q = tid&31, d = (tid>>5)*8) ----
  const int q = threadIdx.x & 31;
  const int dd = (threadIdx.x >> 5) * 8;
  float2 ml0 = mlS[q], ml1 = mlS[32 + q], ml2 = mlS[64 + q], ml3 = mlS[96 + q];
  float M = fmaxf(fmaxf(ml0.x, ml1.x), fmaxf(ml2.x, ml3.x));
  float w0 = exp2f(ml0.x - M), w1 = exp2f(ml1.x - M);
  float w2 = exp2f(ml2.x - M), w3 = exp2f(ml3.x - M);
  float L = ml0.y * w0 + ml1.y * w1 + ml2.y * w2 + ml3.y * w3;
  const int offA = (q << 6) + (dd ^ ((q & 15) << 2));
  const int offB = offA ^ 4;
  float o[8];
  {
    float4 xa = *(float4*)(accS + offA);
    float4 xb = *(float4*)(accS + offB);
    o[0] = w0 * xa.x; o[1] = w0 * xa.y; o[2] = w0 * xa.z; o[3] = w0 * xa.w;
    o[4] = w0 * xb.x; o[5] = w0 * xb.y; o[6] = w0 * xb.z; o[7] = w0 * xb.w;
  }
  {
    float4 xa = *(float4*)(accS + 2048 + offA);
    float4 xb = *(float4*)(accS + 2048 + offB);
    o[0] += w1 * xa.x; o[1] += w1 * xa.y; o[2] += w1 * xa.z; o[3] += w1 * xa.w;
    o[4] += w1 * xb.x; o[5] += w1 * xb.y; o[6] += w1 * xb.z; o[7] += w1 * xb.w;
  }
  {
    float4 xa = *(float4*)(accS + 4096 + offA);
    float4 xb = *(float4*)(accS + 4096 + offB);
    o[0] += w2 * xa.x; o[1] += w2 * xa.y; o[2] += w2 * xa.z; o[3] += w2 * xa.w;
    o[4] += w2 * xb.x; o[5] += w2 * xb.y; o[6] += w2 * xb.z; o[7] += w2 * xb.w;
  }
  {
    float4 xa = *(float4*)(accS + 6144 + offA);
    float4 xb = *(float4*)(accS + 6144 + offB);
    o[0] += w3 * xa.x; o[1] += w3 * xa.y; o[2] += w3 * xa.z; o[3] += w3 * xa.w;
    o[4] += w3 * xb.x; o[5] += w3 * xb.y; o[6] += w3 * xb.z; o[7] += w3 * xb.w;
  }
  const float invL = 1.0f / L;
  uint4 pk;
  pk.x = cvtpk_bf16(o[0] * invL, o[1] * invL);
  pk.y = cvtpk_bf16(o[2] * invL, o[3] * invL);
  pk.z = cvtpk_bf16(o[4] * invL, o[5] * invL);
  pk.w = cvtpk_bf16(o[6] * invL, o[7] * invL);
  *(uint4*)(Aout + (size_t)(q0 + q) * HIDDEN + h * 64 + dd) = pk;
}

// ---------------- launch ----------------

extern "C" void kernel_launch(void* const* d_in, const int* in_sizes, int n_in,
                              void* d_out, int out_size, void* d_ws, size_t ws_size,
                              hipStream_t stream) {
  const float* hidden  = (const float*)d_in[0];
  const float* webmask = (const float*)d_in[3];
  const float* Wq = (const float*)d_in[4];
  const float* Wk = (const float*)d_in[5];
  const float* Wv = (const float*)d_in[6];
  const float* Wo = (const float*)d_in[7];
  const float* qlnw = (const float*)d_in[8];
  const float* klnw = (const float*)d_in[9];
  float* out = (float*)d_out;

  char* ws = (char*)d_ws;
  u16*      hbf  = (u16*)(ws);                         // 8 MB  hidden bf16
  u16*      Wcat = (u16*)(ws + (8u << 20));            // 12 MB QKV weights^T
  u16*      Wot  = (u16*)(ws + (20u << 20));           // 8 MB  Wo^T
  float*    qkv  = (float*)(ws + (28u << 20));         // 24 MB QKV fp32
  u16*      Qh   = (u16*)(ws + (52u << 20));           // 8 MB  Q' (pre-scaled)
  u16*      Kh   = (u16*)(ws + (60u << 20));           // 2 MB  K'
  u16*      Vt   = (u16*)(ws + (62u << 20));           // 2 MB  V^T
  u16*      Ao   = (u16*)(ws + (64u << 20));           // 8 MB  attn out bf16
  uint32_t* mb   = (uint32_t*)(ws + (72u << 20));      // 0.5 MB web mask bits

  cvt_f32_bf16<<<4096, 256, 0, stream>>>(hidden, hbf);
  transpose_w<<<dim3(64, 64), 256, 0, stream>>>(Wq, 2048, Wcat, 2048);
  transpose_w<<<dim3(64, 16), 256, 0, stream>>>(Wk, 512, Wcat + (size_t)2048 * 2048, 2048);
  transpose_w<<<dim3(64, 16), 256, 0, stream>>>(Wv, 512, Wcat + (size_t)2560 * 2048, 2048);
  transpose_w<<<dim3(64, 64), 256, 0, stream>>>(Wo, 2048, Wot, 2048);
  pack_mask<<<512, 256, 0, stream>>>(webmask, mb);

  gemm_tn<<<768, 256, 0, stream>>>(hbf, Wcat, qkv, SLEN, QKVN, HIDDEN);
  rope_rms<<<dim3(512, 40), 256, 0, stream>>>(qkv, qlnw, klnw, Qh, Kh);
  v_trans<<<dim3(64, 8), 256, 0, stream>>>(qkv, Vt);
  attn_fused<<<2048, 256, 0, stream>>>(Qh, Kh, Vt, mb, Ao);
  gemm_tn<<<512, 256, 0, stream>>>(Ao, Wot, out, SLEN, HIDDEN, HIDDEN);
}

// Round 12
// 241.292 us; speedup vs baseline: 1.0823x; 1.0328x over previous
//
#include <hip/hip_runtime.h>
#include <stdint.h>

// WebAttention fused block for MI355X (gfx950).
// R12: diagnostic + launch-overhead round. (1) attn split into two 16-head
//      dispatches (~47us each) so the GEMMs can surface in rocprof top-5.
//      (2) 6 prep kernels merged into prep_all; rope+v_trans merged. 11->6
//      launches. All math bodies verbatim from R11.

typedef unsigned short u16;
typedef unsigned short u16x4 __attribute__((ext_vector_type(4)));
typedef unsigned short u16x8 __attribute__((ext_vector_type(8)));
typedef __bf16 bf16x8 __attribute__((ext_vector_type(8)));
typedef float f32x4 __attribute__((ext_vector_type(4)));
typedef float f32x16 __attribute__((ext_vector_type(16)));

#define SLEN 2048
#define HIDDEN 2048
#define QKVN 3072   // 2048 Q + 512 K + 512 V
// Q pre-scale: 1/sqrt(64) * log2(e)  -> scores land in exp2 domain
#define QSCALE 0.18033688011112042f

__device__ __forceinline__ u16 f2bf(float x) {  // RNE, matches numpy/JAX
  uint32_t u = __float_as_uint(x);
  return (u16)((u + 0x7FFFu + ((u >> 16) & 1u)) >> 16);
}

__device__ __forceinline__ uint32_t cvtpk_bf16(float lo, float hi) {
  uint32_t r;
  asm("v_cvt_pk_bf16_f32 %0, %1, %2" : "=v"(r) : "v"(lo), "v"(hi));
  return r;
}

// Cross-half (lane ^ 32) reductions: {r[0],r[1]} = {self, partner} as a set.
__device__ __forceinline__ float xhalf_max(float x) {
  auto r = __builtin_amdgcn_permlane32_swap(__float_as_uint(x), __float_as_uint(x),
                                            false, false);
  return fmaxf(__uint_as_float(r[0]), __uint_as_float(r[1]));
}

__device__ __forceinline__ float xhalf_sum(float x) {
  auto r = __builtin_amdgcn_permlane32_swap(__float_as_uint(x), __float_as_uint(x),
                                            false, false);
  return __uint_as_float(r[0]) + __uint_as_float(r[1]);
}

__device__ __forceinline__ void gload_lds16(const void* g, void* l) {
  __builtin_amdgcn_global_load_lds(
      (const __attribute__((address_space(1))) void*)g,
      (__attribute__((address_space(3))) void*)l, 16, 0, 0);
}

// ---------------- prep_all: cvt + 4 transposes + pack_mask in one kernel -----
// blockIdx ranges: [0,4096) cvt | [4096,8192) Wq | [8192,9216) Wk |
// [9216,10240) Wv | [10240,14336) Wo | [14336,14848) pack_mask.
__device__ __forceinline__ void transpose_tile(const float* in, int ldin,
                                               u16* out, int ldout,
                                               int k0, int n0, int tid,
                                               float (*tile)[33]) {
  int x = tid & 31, y = tid >> 5;  // y in 0..7
#pragma unroll
  for (int i = 0; i < 32; i += 8)
    tile[y + i][x] = in[(size_t)(k0 + y + i) * ldin + n0 + x];
  __syncthreads();
#pragma unroll
  for (int i = 0; i < 32; i += 8)
    out[(size_t)(n0 + y + i) * ldout + k0 + x] = f2bf(tile[x][y + i]);
}

__global__ __launch_bounds__(256) void prep_all(const float* __restrict__ hidden,
                                                u16* __restrict__ hbf,
                                                const float* __restrict__ Wq,
                                                const float* __restrict__ Wk,
                                                const float* __restrict__ Wv,
                                                const float* __restrict__ Wo,
                                                u16* __restrict__ Wcat,
                                                u16* __restrict__ Wot,
                                                const float* __restrict__ webmask,
                                                uint32_t* __restrict__ mbits) {
  __shared__ float tile[32][33];
  const int b = blockIdx.x, tid = threadIdx.x;
  if (b < 4096) {
    int idx = (b * 256 + tid) * 4;
    float4 v = *(const float4*)(hidden + idx);
    u16x4 o;
    o[0] = f2bf(v.x); o[1] = f2bf(v.y); o[2] = f2bf(v.z); o[3] = f2bf(v.w);
    *(u16x4*)(hbf + idx) = o;
  } else if (b < 8192) {
    int t = b - 4096;
    transpose_tile(Wq, 2048, Wcat, 2048, (t & 63) * 32, (t >> 6) * 32, tid, tile);
  } else if (b < 9216) {
    int t = b - 8192;
    transpose_tile(Wk, 512, Wcat + (size_t)2048 * 2048, 2048,
                   (t & 63) * 32, (t >> 6) * 32, tid, tile);
  } else if (b < 10240) {
    int t = b - 9216;
    transpose_tile(Wv, 512, Wcat + (size_t)2560 * 2048, 2048,
                   (t & 63) * 32, (t >> 6) * 32, tid, tile);
  } else if (b < 14336) {
    int t = b - 10240;
    transpose_tile(Wo, 2048, Wot, 2048, (t & 63) * 32, (t >> 6) * 32, tid, tile);
  } else {
    int w = (b - 14336) * 256 + tid;  // 2048*64 words
    const float* p = webmask + (size_t)w * 32;
    uint32_t bits = 0;
#pragma unroll
    for (int j = 0; j < 32; ++j) bits |= (p[j] > -0.5f ? 1u : 0u) << j;
    mbits[w] = bits;
  }
}

// ---------------- TN GEMM: C[M][N] = A[M][K] * B[N][K]^T (bf16 in, fp32 out) --------
// 64x128 tile, BK=64, 4 waves (2x2), 32x64/wave, fragment-ordered LDS.
// 1-D grid + XCD-chunk remap (R11): xcd = lin&7 owns bm in [4*xcd, 4*xcd+4).
__global__ __launch_bounds__(256) void gemm_tn(const u16* __restrict__ A,
                                               const u16* __restrict__ B,
                                               float* __restrict__ C,
                                               int M, int N, int K) {
  __shared__ u16 As[64 * 64];    // 8 KB
  __shared__ u16 Bs[128 * 64];   // 16 KB
  const int tid = threadIdx.x;
  const int w = tid >> 6, l = tid & 63;
  const int lin = blockIdx.x;
  const int xcd = lin & 7, pos = lin >> 3;
  const int bm = xcd * 4 + (pos & 3);
  const int bn = pos >> 2;
  const int wr = w >> 1, wc = w & 1;

  f32x4 acc[2][4] = {};

  int rowA[2], colA[2], ldsA[2];
#pragma unroll
  for (int g = 0; g < 2; ++g) {
    int c = g * 256 + w * 64 + l;
    rowA[g] = ((c >> 7) << 4) + (c & 15);
    colA[g] = ((c >> 4) & 7) * 8;
    ldsA[g] = (g * 256 + w * 64) * 8;
  }
  int rowB[4], colB[4], ldsB[4];
#pragma unroll
  for (int g = 0; g < 4; ++g) {
    int c = g * 256 + w * 64 + l;
    rowB[g] = ((c >> 7) << 4) + (c & 15);
    colB[g] = ((c >> 4) & 7) * 8;
    ldsB[g] = (g * 256 + w * 64) * 8;
  }
  const u16* Arow = A + (size_t)(bm * 64) * K;
  const u16* Brow = B + (size_t)(bn * 128) * K;

  for (int k0 = 0; k0 < K; k0 += 64) {
    __syncthreads();
#pragma unroll
    for (int g = 0; g < 2; ++g)
      gload_lds16(Arow + (size_t)rowA[g] * K + k0 + colA[g], &As[ldsA[g]]);
#pragma unroll
    for (int g = 0; g < 4; ++g)
      gload_lds16(Brow + (size_t)rowB[g] * K + k0 + colB[g], &Bs[ldsB[g]]);
    asm volatile("s_waitcnt vmcnt(0)" ::: "memory");
    __syncthreads();
#pragma unroll
    for (int ks = 0; ks < 2; ++ks) {
      bf16x8 af[2], bfr[4];
#pragma unroll
      for (int mi = 0; mi < 2; ++mi)
        af[mi] = *(const bf16x8*)&As[(wr * 2 + mi) * 1024 + ks * 512 + l * 8];
#pragma unroll
      for (int ni = 0; ni < 4; ++ni)
        bfr[ni] = *(const bf16x8*)&Bs[(wc * 4 + ni) * 1024 + ks * 512 + l * 8];
#pragma unroll
      for (int mi = 0; mi < 2; ++mi)
#pragma unroll
        for (int ni = 0; ni < 4; ++ni)
          acc[mi][ni] = __builtin_amdgcn_mfma_f32_16x16x32_bf16(af[mi], bfr[ni],
                                                                acc[mi][ni], 0, 0, 0);
    }
  }
  const int cr = (l >> 4) * 4, cc = l & 15;
#pragma unroll
  for (int mi = 0; mi < 2; ++mi) {
    int row0 = bm * 64 + wr * 32 + mi * 16 + cr;
#pragma unroll
    for (int ni = 0; ni < 4; ++ni) {
      int col = bn * 128 + wc * 64 + ni * 16 + cc;
#pragma unroll
      for (int i = 0; i < 4; ++i)
        C[(size_t)(row0 + i) * N + col] = acc[mi][ni][i];
    }
  }
}

// ---------------- RoPE/RMSNorm + V-transpose, one kernel ----------------
// blockIdx ranges: [0,20480) rope (bx=b&511, hh=b>>9) | [20480,20992) v_trans.
__global__ __launch_bounds__(256) void rope_vtrans(const float* __restrict__ qkv,
                                                   const float* __restrict__ qw,
                                                   const float* __restrict__ kw,
                                                   u16* __restrict__ Qo,
                                                   u16* __restrict__ Ko,
                                                   u16* __restrict__ Vt) {
  __shared__ float tile[32][65];
  const int b = blockIdx.x, tid = threadIdx.x;
  if (b < 20480) {
    int s = (b & 511) * 4 + (tid >> 6);
    int hh = b >> 9;
    int d = tid & 63;
    bool isq = hh < 32;
    int col = isq ? hh * 64 + d : 2048 + (hh - 32) * 64 + d;
    float x = qkv[(size_t)s * QKVN + col];
    int i = d & 31;
    float inv_freq = exp2f(-(float)i * (13.287712379549449f / 32.0f));
    float ang = (float)s * inv_freq;
    float sn, cs;
    __sincosf(ang, &sn, &cs);
    float partner = __shfl_xor(x, 32, 64);
    float y = (d < 32) ? (x * cs - partner * sn) : (x * cs + partner * sn);
    float ss = y * y;
#pragma unroll
    for (int off = 32; off; off >>= 1) ss += __shfl_xor(ss, off, 64);
    float r = rsqrtf(ss * (1.0f / 64.0f) + 1e-6f);
    float o = y * r * (isq ? qw[d] : kw[d]);
    if (isq) Qo[((size_t)hh * SLEN + s) * 64 + d] = f2bf(o * QSCALE);
    else     Ko[((size_t)(hh - 32) * SLEN + s) * 64 + d] = f2bf(o);
  } else {
    int t = b - 20480;
    int kv = t >> 6;
    int s0 = (t & 63) * 32;
    int d = tid & 63, r4 = tid >> 6;
#pragma unroll
    for (int i = 0; i < 32; i += 4)
      tile[i + r4][d] = qkv[(size_t)(s0 + i + r4) * QKVN + 2560 + kv * 64 + d];
    __syncthreads();
    int dr = tid >> 2, sc = (tid & 3) * 8;
    u16x8 o;
#pragma unroll
    for (int j = 0; j < 8; ++j) o[j] = f2bf(tile[sc + j][dr]);
    *(u16x8*)(Vt + ((size_t)(kv * 64 + dr)) * SLEN + s0 + sc) = o;
  }
}

// ---------------- flash attention, in-block split-K x4, 16 heads/dispatch ----
// grid 1024, hoff in {0,16}: xcd = lin&7 owns heads {hoff+2*xcd, hoff+2*xcd+1}
// (one kv head per XCD -> K/V L2-resident). qt = 63-(pos>>1): longest first.
// Wave w takes kb = w, w+4, ...; LDS combine; Ao written directly.
__global__ __launch_bounds__(256) void attn_fused(const u16* __restrict__ Q,
                                                  const u16* __restrict__ Kh,
                                                  const u16* __restrict__ Vt,
                                                  const uint32_t* __restrict__ mbits,
                                                  u16* __restrict__ Aout,
                                                  int hoff) {
  __shared__ float accS[4 * 32 * 64];  // 32 KB
  __shared__ float2 mlS[4 * 32];       // 1 KB
  const int w = threadIdx.x >> 6, l = threadIdx.x & 63;
  const int lin = blockIdx.x;
  const int xcd = lin & 7, pos = lin >> 3;
  const int h = hoff + xcd * 2 + (pos & 1);  // 2 heads/XCD = one kv head
  const int qt = 63 - (pos >> 1);            // longest blocks dispatched first
  const int q0 = qt * 32;
  const int hkv = h >> 2;
  const bool web = (h >= 16);
  const int l31 = l & 31, hi = l >> 5;
  const int qrel = l31 - 4 * hi;  // diag-block causal: keep iff ki <= qrel
  const int nkb = qt + 1;

  const u16* Qp = Q + ((size_t)h * SLEN + q0 + l31) * 64 + hi * 8;
  bf16x8 qf0 = *(const bf16x8*)(Qp);
  bf16x8 qf1 = *(const bf16x8*)(Qp + 16);
  bf16x8 qf2 = *(const bf16x8*)(Qp + 32);
  bf16x8 qf3 = *(const bf16x8*)(Qp + 48);

  const u16* Kp = Kh + ((size_t)hkv * SLEN + l31) * 64 + hi * 8;
  const u16* Vp = Vt + ((size_t)hkv * 64 + l31) * SLEN + hi * 8;
  const uint32_t* mrow = mbits + (size_t)(q0 + l31) * 64;

  f32x16 acc0 = {}, acc1 = {};   // O^T[d][q]
  float m = -1e30f, ll = 0.f;

  if (w < nkb) {
    const u16* kp = Kp + (size_t)w * 64 * 32;
    bf16x8 kc0 = *(const bf16x8*)(kp);
    bf16x8 kc1 = *(const bf16x8*)(kp + 16);
    bf16x8 kc2 = *(const bf16x8*)(kp + 32);
    bf16x8 kc3 = *(const bf16x8*)(kp + 48);
    const u16* vp0 = Vp + w * 32;
    bf16x8 vc00 = *(const bf16x8*)(vp0);
    bf16x8 vc01 = *(const bf16x8*)(vp0 + 16);
    bf16x8 vc10 = *(const bf16x8*)(vp0 + 32 * SLEN);
    bf16x8 vc11 = *(const bf16x8*)(vp0 + 32 * SLEN + 16);
    uint32_t wcur = web ? mrow[w] : 0u;

    for (int kb = w; kb < nkb; kb += 4) {
      bf16x8 kn0, kn1, kn2, kn3, vn00, vn01, vn10, vn11;
      uint32_t wnext = 0u;
      if (kb + 4 < nkb) {
        const u16* knp = Kp + (size_t)(kb + 4) * 64 * 32;
        kn0 = *(const bf16x8*)(knp);
        kn1 = *(const bf16x8*)(knp + 16);
        kn2 = *(const bf16x8*)(knp + 32);
        kn3 = *(const bf16x8*)(knp + 48);
        const u16* vnp = Vp + (kb + 4) * 32;
        vn00 = *(const bf16x8*)(vnp);
        vn01 = *(const bf16x8*)(vnp + 16);
        vn10 = *(const bf16x8*)(vnp + 32 * SLEN);
        vn11 = *(const bf16x8*)(vnp + 32 * SLEN + 16);
        if (web) wnext = mrow[kb + 4];
      }
      f32x16 s = {};
      s = __builtin_amdgcn_mfma_f32_32x32x16_bf16(kc0, qf0, s, 0, 0, 0);
      s = __builtin_amdgcn_mfma_f32_32x32x16_bf16(kc1, qf1, s, 0, 0, 0);
      s = __builtin_amdgcn_mfma_f32_32x32x16_bf16(kc2, qf2, s, 0, 0, 0);
      s = __builtin_amdgcn_mfma_f32_32x32x16_bf16(kc3, qf3, s, 0, 0, 0);
      if (web) {
        uint32_t word = wcur >> (hi * 4);
        if (kb == qt) {
#pragma unroll
          for (int r = 0; r < 16; ++r) {
            const int ki = (r & 3) + 8 * (r >> 2);
            bool keep = ((word >> ki) & 1u) && (ki <= qrel);
            s[r] = keep ? s[r] : -1e9f;
          }
        } else {
#pragma unroll
          for (int r = 0; r < 16; ++r) {
            const int ki = (r & 3) + 8 * (r >> 2);
            s[r] = ((word >> ki) & 1u) ? s[r] : -1e9f;
          }
        }
      } else if (kb == qt) {
#pragma unroll
        for (int r = 0; r < 16; ++r) {
          const int ki = (r & 3) + 8 * (r >> 2);
          s[r] = (ki <= qrel) ? s[r] : -1e9f;
        }
      }
      float pm = s[0];
#pragma unroll
      for (int r = 1; r < 16; ++r) pm = fmaxf(pm, s[r]);
      pm = xhalf_max(pm);
      if (__any(pm > m + 8.0f)) {           // defer-max, log2 units
        float nm = fmaxf(m, pm);
        float al = exp2f(m - nm);
#pragma unroll
        for (int r = 0; r < 16; ++r) { acc0[r] *= al; acc1[r] *= al; }
        ll *= al;
        m = nm;
      }
      f32x16 p;
#pragma unroll
      for (int r = 0; r < 16; ++r) p[r] = exp2f(s[r] - m);
      float rs = 0.f;
#pragma unroll
      for (int r = 0; r < 16; ++r) rs += p[r];
      ll += xhalf_sum(rs);
      uint32_t a0 = cvtpk_bf16(p[0], p[1]),   b0 = cvtpk_bf16(p[2], p[3]);
      uint32_t c0 = cvtpk_bf16(p[4], p[5]),   d0 = cvtpk_bf16(p[6], p[7]);
      uint32_t a1 = cvtpk_bf16(p[8], p[9]),   b1 = cvtpk_bf16(p[10], p[11]);
      uint32_t c1 = cvtpk_bf16(p[12], p[13]), d1 = cvtpk_bf16(p[14], p[15]);
      auto r0 = __builtin_amdgcn_permlane32_swap(a0, c0, false, false);
      auto r1 = __builtin_amdgcn_permlane32_swap(b0, d0, false, false);
      auto r2 = __builtin_amdgcn_permlane32_swap(a1, c1, false, false);
      auto r3 = __builtin_amdgcn_permlane32_swap(b1, d1, false, false);
      union { uint32_t w[4]; bf16x8 v; } pf0u, pf1u;
      pf0u.w[0] = r0[0]; pf0u.w[1] = r1[0]; pf0u.w[2] = r0[1]; pf0u.w[3] = r1[1];
      pf1u.w[0] = r2[0]; pf1u.w[1] = r3[0]; pf1u.w[2] = r2[1]; pf1u.w[3] = r3[1];
      acc0 = __builtin_amdgcn_mfma_f32_32x32x16_bf16(vc00, pf0u.v, acc0, 0, 0, 0);
      acc0 = __builtin_amdgcn_mfma_f32_32x32x16_bf16(vc01, pf1u.v, acc0, 0, 0, 0);
      acc1 = __builtin_amdgcn_mfma_f32_32x32x16_bf16(vc10, pf0u.v, acc1, 0, 0, 0);
      acc1 = __builtin_amdgcn_mfma_f32_32x32x16_bf16(vc11, pf1u.v, acc1, 0, 0, 0);
      kc0 = kn0; kc1 = kn1; kc2 = kn2; kc3 = kn3;
      vc00 = vn00; vc01 = vn01; vc10 = vn10; vc11 = vn11;
      wcur = wnext;
    }
  }
  // ---- stash per-wave state in LDS (raw acc + m,l) ----
  if (hi == 0) mlS[w * 32 + l31] = make_float2(m, ll);
  float* wbase = accS + w * 2048 + (l31 << 6);
  const int sw = (l31 & 15) << 2;  // swizzle: d ^= sw
#pragma unroll
  for (int t = 0; t < 4; ++t) {
    int dA = (8 * t + 4 * hi) ^ sw;
    int dB = (32 + 8 * t + 4 * hi) ^ sw;
    float4 v0 = {acc0[4 * t], acc0[4 * t + 1], acc0[4 * t + 2], acc0[4 * t + 3]};
    float4 v1 = {acc1[4 * t], acc1[4 * t + 1], acc1[4 * t + 2], acc1[4 * t + 3]};
    *(float4*)(wbase + dA) = v0;
    *(float4*)(wbase + dB) = v1;
  }
  __syncthreads();
  // ---- combine: thread -> (q = tid&31, d = (tid>>5)*8) ----
  const int q = threadIdx.x & 31;
  const int dd = (threadIdx.x >> 5) * 8;
  float2 ml0 = mlS[q], ml1 = mlS[32 + q], ml2 = mlS[64 + q], ml3 = mlS[96 + q];
  float M = fmaxf(fmaxf(ml0.x, ml1.x), fmaxf(ml2.x, ml3.x));
  float w0 = exp2f(ml0.x - M), w1 = exp2f(ml1.x - M);
  float w2 = exp2f(ml2.x - M), w3 = exp2f(ml3.x - M);
  float L = ml0.y * w0 + ml1.y * w1 + ml2.y * w2 + ml3.y * w3;
  const int offA = (q << 6) + (dd ^ ((q & 15) << 2));
  const int offB = offA ^ 4;
  float o[8];
  {
    float4 xa = *(float4*)(accS + offA);
    float4 xb = *(float4*)(accS + offB);
    o[0] = w0 * xa.x; o[1] = w0 * xa.y; o[2] = w0 * xa.z; o[3] = w0 * xa.w;
    o[4] = w0 * xb.x; o[5] = w0 * xb.y; o[6] = w0 * xb.z; o[7] = w0 * xb.w;
  }
  {
    float4 xa = *(float4*)(accS + 2048 + offA);
    float4 xb = *(float4*)(accS + 2048 + offB);
    o[0] += w1 * xa.x; o[1] += w1 * xa.y; o[2] += w1 * xa.z; o[3] += w1 * xa.w;
    o[4] += w1 * xb.x; o[5] += w1 * xb.y; o[6] += w1 * xb.z; o[7] += w1 * xb.w;
  }
  {
    float4 xa = *(float4*)(accS + 4096 + offA);
    float4 xb = *(float4*)(accS + 4096 + offB);
    o[0] += w2 * xa.x; o[1] += w2 * xa.y; o[2] += w2 * xa.z; o[3] += w2 * xa.w;
    o[4] += w2 * xb.x; o[5] += w2 * xb.y; o[6] += w2 * xb.z; o[7] += w2 * xb.w;
  }
  {
    float4 xa = *(float4*)(accS + 6144 + offA);
    float4 xb = *(float4*)(accS + 6144 + offB);
    o[0] += w3 * xa.x; o[1] += w3 * xa.y; o[2] += w3 * xa.z; o[3] += w3 * xa.w;
    o[4] += w3 * xb.x; o[5] += w3 * xb.y; o[6] += w3 * xb.z; o[7] += w3 * xb.w;
  }
  const float invL = 1.0f / L;
  uint4 pk;
  pk.x = cvtpk_bf16(o[0] * invL, o[1] * invL);
  pk.y = cvtpk_bf16(o[2] * invL, o[3] * invL);
  pk.z = cvtpk_bf16(o[4] * invL, o[5] * invL);
  pk.w = cvtpk_bf16(o[6] * invL, o[7] * invL);
  *(uint4*)(Aout + (size_t)(q0 + q) * HIDDEN + h * 64 + dd) = pk;
}

// ---------------- launch ----------------

extern "C" void kernel_launch(void* const* d_in, const int* in_sizes, int n_in,
                              void* d_out, int out_size, void* d_ws, size_t ws_size,
                              hipStream_t stream) {
  const float* hidden  = (const float*)d_in[0];
  const float* webmask = (const float*)d_in[3];
  const float* Wq = (const float*)d_in[4];
  const float* Wk = (const float*)d_in[5];
  const float* Wv = (const float*)d_in[6];
  const float* Wo = (const float*)d_in[7];
  const float* qlnw = (const float*)d_in[8];
  const float* klnw = (const float*)d_in[9];
  float* out = (float*)d_out;

  char* ws = (char*)d_ws;
  u16*      hbf  = (u16*)(ws);                         // 8 MB  hidden bf16
  u16*      Wcat = (u16*)(ws + (8u << 20));            // 12 MB QKV weights^T
  u16*      Wot  = (u16*)(ws + (20u << 20));           // 8 MB  Wo^T
  float*    qkv  = (float*)(ws + (28u << 20));         // 24 MB QKV fp32
  u16*      Qh   = (u16*)(ws + (52u << 20));           // 8 MB  Q' (pre-scaled)
  u16*      Kh   = (u16*)(ws + (60u << 20));           // 2 MB  K'
  u16*      Vt   = (u16*)(ws + (62u << 20));           // 2 MB  V^T
  u16*      Ao   = (u16*)(ws + (64u << 20));           // 8 MB  attn out bf16
  uint32_t* mb   = (uint32_t*)(ws + (72u << 20));      // 0.5 MB web mask bits

  prep_all<<<14848, 256, 0, stream>>>(hidden, hbf, Wq, Wk, Wv, Wo, Wcat, Wot,
                                      webmask, mb);
  gemm_tn<<<768, 256, 0, stream>>>(hbf, Wcat, qkv, SLEN, QKVN, HIDDEN);
  rope_vtrans<<<20992, 256, 0, stream>>>(qkv, qlnw, klnw, Qh, Kh, Vt);
  attn_fused<<<1024, 256, 0, stream>>>(Qh, Kh, Vt, mb, Ao, 0);
  attn_fused<<<1024, 256, 0, stream>>>(Qh, Kh, Vt, mb, Ao, 16);
  gemm_tn<<<512, 256, 0, stream>>>(Ao, Wot, out, SLEN, HIDDEN, HIDDEN);
}

// Round 13
// 241.132 us; speedup vs baseline: 1.0830x; 1.0007x over previous
//
#include <hip/hip_runtime.h>
#include <stdint.h>

// WebAttention fused block for MI355X (gfx950).
// R13: gemm_tn -> 2-phase double-buffered K-loop (T3-minimum): issue next tile's
//      global_load_lds BEFORE computing current tile; vmcnt(0)+one barrier per
//      iter. Load latency (~600-900cyc L2/L3) overlaps compute instead of
//      serializing (R12 profile: MfmaUtil 12.5%, all pipes idle = latency-bound).
//      Everything else unchanged from R12.

typedef unsigned short u16;
typedef unsigned short u16x4 __attribute__((ext_vector_type(4)));
typedef unsigned short u16x8 __attribute__((ext_vector_type(8)));
typedef __bf16 bf16x8 __attribute__((ext_vector_type(8)));
typedef float f32x4 __attribute__((ext_vector_type(4)));
typedef float f32x16 __attribute__((ext_vector_type(16)));

#define SLEN 2048
#define HIDDEN 2048
#define QKVN 3072   // 2048 Q + 512 K + 512 V
// Q pre-scale: 1/sqrt(64) * log2(e)  -> scores land in exp2 domain
#define QSCALE 0.18033688011112042f

__device__ __forceinline__ u16 f2bf(float x) {  // RNE, matches numpy/JAX
  uint32_t u = __float_as_uint(x);
  return (u16)((u + 0x7FFFu + ((u >> 16) & 1u)) >> 16);
}

__device__ __forceinline__ uint32_t cvtpk_bf16(float lo, float hi) {
  uint32_t r;
  asm("v_cvt_pk_bf16_f32 %0, %1, %2" : "=v"(r) : "v"(lo), "v"(hi));
  return r;
}

// Cross-half (lane ^ 32) reductions: {r[0],r[1]} = {self, partner} as a set.
__device__ __forceinline__ float xhalf_max(float x) {
  auto r = __builtin_amdgcn_permlane32_swap(__float_as_uint(x), __float_as_uint(x),
                                            false, false);
  return fmaxf(__uint_as_float(r[0]), __uint_as_float(r[1]));
}

__device__ __forceinline__ float xhalf_sum(float x) {
  auto r = __builtin_amdgcn_permlane32_swap(__float_as_uint(x), __float_as_uint(x),
                                            false, false);
  return __uint_as_float(r[0]) + __uint_as_float(r[1]);
}

__device__ __forceinline__ void gload_lds16(const void* g, void* l) {
  __builtin_amdgcn_global_load_lds(
      (const __attribute__((address_space(1))) void*)g,
      (__attribute__((address_space(3))) void*)l, 16, 0, 0);
}

// ---------------- prep_all: cvt + 4 transposes + pack_mask in one kernel -----
__device__ __forceinline__ void transpose_tile(const float* in, int ldin,
                                               u16* out, int ldout,
                                               int k0, int n0, int tid,
                                               float (*tile)[33]) {
  int x = tid & 31, y = tid >> 5;  // y in 0..7
#pragma unroll
  for (int i = 0; i < 32; i += 8)
    tile[y + i][x] = in[(size_t)(k0 + y + i) * ldin + n0 + x];
  __syncthreads();
#pragma unroll
  for (int i = 0; i < 32; i += 8)
    out[(size_t)(n0 + y + i) * ldout + k0 + x] = f2bf(tile[x][y + i]);
}

__global__ __launch_bounds__(256) void prep_all(const float* __restrict__ hidden,
                                                u16* __restrict__ hbf,
                                                const float* __restrict__ Wq,
                                                const float* __restrict__ Wk,
                                                const float* __restrict__ Wv,
                                                const float* __restrict__ Wo,
                                                u16* __restrict__ Wcat,
                                                u16* __restrict__ Wot,
                                                const float* __restrict__ webmask,
                                                uint32_t* __restrict__ mbits) {
  __shared__ float tile[32][33];
  const int b = blockIdx.x, tid = threadIdx.x;
  if (b < 4096) {
    int idx = (b * 256 + tid) * 4;
    float4 v = *(const float4*)(hidden + idx);
    u16x4 o;
    o[0] = f2bf(v.x); o[1] = f2bf(v.y); o[2] = f2bf(v.z); o[3] = f2bf(v.w);
    *(u16x4*)(hbf + idx) = o;
  } else if (b < 8192) {
    int t = b - 4096;
    transpose_tile(Wq, 2048, Wcat, 2048, (t & 63) * 32, (t >> 6) * 32, tid, tile);
  } else if (b < 9216) {
    int t = b - 8192;
    transpose_tile(Wk, 512, Wcat + (size_t)2048 * 2048, 2048,
                   (t & 63) * 32, (t >> 6) * 32, tid, tile);
  } else if (b < 10240) {
    int t = b - 9216;
    transpose_tile(Wv, 512, Wcat + (size_t)2560 * 2048, 2048,
                   (t & 63) * 32, (t >> 6) * 32, tid, tile);
  } else if (b < 14336) {
    int t = b - 10240;
    transpose_tile(Wo, 2048, Wot, 2048, (t & 63) * 32, (t >> 6) * 32, tid, tile);
  } else {
    int w = (b - 14336) * 256 + tid;  // 2048*64 words
    const float* p = webmask + (size_t)w * 32;
    uint32_t bits = 0;
#pragma unroll
    for (int j = 0; j < 32; ++j) bits |= (p[j] > -0.5f ? 1u : 0u) << j;
    mbits[w] = bits;
  }
}

// ---------------- TN GEMM: C[M][N] = A[M][K] * B[N][K]^T (bf16 in, fp32 out) --------
// 64x128 tile, BK=64, 4 waves (2x2), 32x64/wave, fragment-ordered LDS,
// 2-phase double buffer: stage(next) -> compute(cur) -> vmcnt(0)+barrier -> swap.
// XCD-chunk remap (R11): xcd = lin&7 owns bm in [4*xcd, 4*xcd+4).
__global__ __launch_bounds__(256) void gemm_tn(const u16* __restrict__ A,
                                               const u16* __restrict__ B,
                                               float* __restrict__ C,
                                               int M, int N, int K) {
  __shared__ u16 As[2][64 * 64];    // 2 x 8 KB
  __shared__ u16 Bs[2][128 * 64];   // 2 x 16 KB
  const int tid = threadIdx.x;
  const int w = tid >> 6, l = tid & 63;
  const int lin = blockIdx.x;
  const int xcd = lin & 7, pos = lin >> 3;
  const int bm = xcd * 4 + (pos & 3);
  const int bn = pos >> 2;
  const int wr = w >> 1, wc = w & 1;

  f32x4 acc[2][4] = {};

  int rowA[2], colA[2], ldsA[2];
#pragma unroll
  for (int g = 0; g < 2; ++g) {
    int c = g * 256 + w * 64 + l;
    rowA[g] = ((c >> 7) << 4) + (c & 15);
    colA[g] = ((c >> 4) & 7) * 8;
    ldsA[g] = (g * 256 + w * 64) * 8;
  }
  int rowB[4], colB[4], ldsB[4];
#pragma unroll
  for (int g = 0; g < 4; ++g) {
    int c = g * 256 + w * 64 + l;
    rowB[g] = ((c >> 7) << 4) + (c & 15);
    colB[g] = ((c >> 4) & 7) * 8;
    ldsB[g] = (g * 256 + w * 64) * 8;
  }
  const u16* Arow = A + (size_t)(bm * 64) * K;
  const u16* Brow = B + (size_t)(bn * 128) * K;

  // prologue: stage k0=0 into buffer 0, drain, barrier
#pragma unroll
  for (int g = 0; g < 2; ++g)
    gload_lds16(Arow + (size_t)rowA[g] * K + colA[g], &As[0][ldsA[g]]);
#pragma unroll
  for (int g = 0; g < 4; ++g)
    gload_lds16(Brow + (size_t)rowB[g] * K + colB[g], &Bs[0][ldsB[g]]);
  asm volatile("s_waitcnt vmcnt(0)" ::: "memory");
  __syncthreads();

  int cur = 0;
  for (int k0 = 0; k0 < K; k0 += 64) {
    // ---- issue next tile's loads into the other buffer (async) ----
    if (k0 + 64 < K) {
      const int nxt = cur ^ 1;
#pragma unroll
      for (int g = 0; g < 2; ++g)
        gload_lds16(Arow + (size_t)rowA[g] * K + k0 + 64 + colA[g], &As[nxt][ldsA[g]]);
#pragma unroll
      for (int g = 0; g < 4; ++g)
        gload_lds16(Brow + (size_t)rowB[g] * K + k0 + 64 + colB[g], &Bs[nxt][ldsB[g]]);
    }
    // ---- compute current buffer (loads for it landed last iter) ----
#pragma unroll
    for (int ks = 0; ks < 2; ++ks) {
      bf16x8 af[2], bfr[4];
#pragma unroll
      for (int mi = 0; mi < 2; ++mi)
        af[mi] = *(const bf16x8*)&As[cur][(wr * 2 + mi) * 1024 + ks * 512 + l * 8];
#pragma unroll
      for (int ni = 0; ni < 4; ++ni)
        bfr[ni] = *(const bf16x8*)&Bs[cur][(wc * 4 + ni) * 1024 + ks * 512 + l * 8];
#pragma unroll
      for (int mi = 0; mi < 2; ++mi)
#pragma unroll
        for (int ni = 0; ni < 4; ++ni)
          acc[mi][ni] = __builtin_amdgcn_mfma_f32_16x16x32_bf16(af[mi], bfr[ni],
                                                                acc[mi][ni], 0, 0, 0);
    }
    // ---- next-buffer loads done + all waves finished reading cur ----
    asm volatile("s_waitcnt vmcnt(0)" ::: "memory");
    __syncthreads();
    cur ^= 1;
  }
  const int cr = (l >> 4) * 4, cc = l & 15;
#pragma unroll
  for (int mi = 0; mi < 2; ++mi) {
    int row0 = bm * 64 + wr * 32 + mi * 16 + cr;
#pragma unroll
    for (int ni = 0; ni < 4; ++ni) {
      int col = bn * 128 + wc * 64 + ni * 16 + cc;
#pragma unroll
      for (int i = 0; i < 4; ++i)
        C[(size_t)(row0 + i) * N + col] = acc[mi][ni][i];
    }
  }
}

// ---------------- RoPE/RMSNorm + V-transpose, one kernel ----------------
__global__ __launch_bounds__(256) void rope_vtrans(const float* __restrict__ qkv,
                                                   const float* __restrict__ qw,
                                                   const float* __restrict__ kw,
                                                   u16* __restrict__ Qo,
                                                   u16* __restrict__ Ko,
                                                   u16* __restrict__ Vt) {
  __shared__ float tile[32][65];
  const int b = blockIdx.x, tid = threadIdx.x;
  if (b < 20480) {
    int s = (b & 511) * 4 + (tid >> 6);
    int hh = b >> 9;
    int d = tid & 63;
    bool isq = hh < 32;
    int col = isq ? hh * 64 + d : 2048 + (hh - 32) * 64 + d;
    float x = qkv[(size_t)s * QKVN + col];
    int i = d & 31;
    float inv_freq = exp2f(-(float)i * (13.287712379549449f / 32.0f));
    float ang = (float)s * inv_freq;
    float sn, cs;
    __sincosf(ang, &sn, &cs);
    float partner = __shfl_xor(x, 32, 64);
    float y = (d < 32) ? (x * cs - partner * sn) : (x * cs + partner * sn);
    float ss = y * y;
#pragma unroll
    for (int off = 32; off; off >>= 1) ss += __shfl_xor(ss, off, 64);
    float r = rsqrtf(ss * (1.0f / 64.0f) + 1e-6f);
    float o = y * r * (isq ? qw[d] : kw[d]);
    if (isq) Qo[((size_t)hh * SLEN + s) * 64 + d] = f2bf(o * QSCALE);
    else     Ko[((size_t)(hh - 32) * SLEN + s) * 64 + d] = f2bf(o);
  } else {
    int t = b - 20480;
    int kv = t >> 6;
    int s0 = (t & 63) * 32;
    int d = tid & 63, r4 = tid >> 6;
#pragma unroll
    for (int i = 0; i < 32; i += 4)
      tile[i + r4][d] = qkv[(size_t)(s0 + i + r4) * QKVN + 2560 + kv * 64 + d];
    __syncthreads();
    int dr = tid >> 2, sc = (tid & 3) * 8;
    u16x8 o;
#pragma unroll
    for (int j = 0; j < 8; ++j) o[j] = f2bf(tile[sc + j][dr]);
    *(u16x8*)(Vt + ((size_t)(kv * 64 + dr)) * SLEN + s0 + sc) = o;
  }
}

// ---------------- flash attention, in-block split-K x4, 16 heads/dispatch ----
__global__ __launch_bounds__(256) void attn_fused(const u16* __restrict__ Q,
                                                  const u16* __restrict__ Kh,
                                                  const u16* __restrict__ Vt,
                                                  const uint32_t* __restrict__ mbits,
                                                  u16* __restrict__ Aout,
                                                  int hoff) {
  __shared__ float accS[4 * 32 * 64];  // 32 KB
  __shared__ float2 mlS[4 * 32];       // 1 KB
  const int w = threadIdx.x >> 6, l = threadIdx.x & 63;
  const int lin = blockIdx.x;
  const int xcd = lin & 7, pos = lin >> 3;
  const int h = hoff + xcd * 2 + (pos & 1);  // 2 heads/XCD = one kv head
  const int qt = 63 - (pos >> 1);            // longest blocks dispatched first
  const int q0 = qt * 32;
  const int hkv = h >> 2;
  const bool web = (h >= 16);
  const int l31 = l & 31, hi = l >> 5;
  const int qrel = l31 - 4 * hi;  // diag-block causal: keep iff ki <= qrel
  const int nkb = qt + 1;

  const u16* Qp = Q + ((size_t)h * SLEN + q0 + l31) * 64 + hi * 8;
  bf16x8 qf0 = *(const bf16x8*)(Qp);
  bf16x8 qf1 = *(const bf16x8*)(Qp + 16);
  bf16x8 qf2 = *(const bf16x8*)(Qp + 32);
  bf16x8 qf3 = *(const bf16x8*)(Qp + 48);

  const u16* Kp = Kh + ((size_t)hkv * SLEN + l31) * 64 + hi * 8;
  const u16* Vp = Vt + ((size_t)hkv * 64 + l31) * SLEN + hi * 8;
  const uint32_t* mrow = mbits + (size_t)(q0 + l31) * 64;

  f32x16 acc0 = {}, acc1 = {};   // O^T[d][q]
  float m = -1e30f, ll = 0.f;

  if (w < nkb) {
    const u16* kp = Kp + (size_t)w * 64 * 32;
    bf16x8 kc0 = *(const bf16x8*)(kp);
    bf16x8 kc1 = *(const bf16x8*)(kp + 16);
    bf16x8 kc2 = *(const bf16x8*)(kp + 32);
    bf16x8 kc3 = *(const bf16x8*)(kp + 48);
    const u16* vp0 = Vp + w * 32;
    bf16x8 vc00 = *(const bf16x8*)(vp0);
    bf16x8 vc01 = *(const bf16x8*)(vp0 + 16);
    bf16x8 vc10 = *(const bf16x8*)(vp0 + 32 * SLEN);
    bf16x8 vc11 = *(const bf16x8*)(vp0 + 32 * SLEN + 16);
    uint32_t wcur = web ? mrow[w] : 0u;

    for (int kb = w; kb < nkb; kb += 4) {
      bf16x8 kn0, kn1, kn2, kn3, vn00, vn01, vn10, vn11;
      uint32_t wnext = 0u;
      if (kb + 4 < nkb) {
        const u16* knp = Kp + (size_t)(kb + 4) * 64 * 32;
        kn0 = *(const bf16x8*)(knp);
        kn1 = *(const bf16x8*)(knp + 16);
        kn2 = *(const bf16x8*)(knp + 32);
        kn3 = *(const bf16x8*)(knp + 48);
        const u16* vnp = Vp + (kb + 4) * 32;
        vn00 = *(const bf16x8*)(vnp);
        vn01 = *(const bf16x8*)(vnp + 16);
        vn10 = *(const bf16x8*)(vnp + 32 * SLEN);
        vn11 = *(const bf16x8*)(vnp + 32 * SLEN + 16);
        if (web) wnext = mrow[kb + 4];
      }
      f32x16 s = {};
      s = __builtin_amdgcn_mfma_f32_32x32x16_bf16(kc0, qf0, s, 0, 0, 0);
      s = __builtin_amdgcn_mfma_f32_32x32x16_bf16(kc1, qf1, s, 0, 0, 0);
      s = __builtin_amdgcn_mfma_f32_32x32x16_bf16(kc2, qf2, s, 0, 0, 0);
      s = __builtin_amdgcn_mfma_f32_32x32x16_bf16(kc3, qf3, s, 0, 0, 0);
      if (web) {
        uint32_t word = wcur >> (hi * 4);
        if (kb == qt) {
#pragma unroll
          for (int r = 0; r < 16; ++r) {
            const int ki = (r & 3) + 8 * (r >> 2);
            bool keep = ((word >> ki) & 1u) && (ki <= qrel);
            s[r] = keep ? s[r] : -1e9f;
          }
        } else {
#pragma unroll
          for (int r = 0; r < 16; ++r) {
            const int ki = (r & 3) + 8 * (r >> 2);
            s[r] = ((word >> ki) & 1u) ? s[r] : -1e9f;
          }
        }
      } else if (kb == qt) {
#pragma unroll
        for (int r = 0; r < 16; ++r) {
          const int ki = (r & 3) + 8 * (r >> 2);
          s[r] = (ki <= qrel) ? s[r] : -1e9f;
        }
      }
      float pm = s[0];
#pragma unroll
      for (int r = 1; r < 16; ++r) pm = fmaxf(pm, s[r]);
      pm = xhalf_max(pm);
      if (__any(pm > m + 8.0f)) {           // defer-max, log2 units
        float nm = fmaxf(m, pm);
        float al = exp2f(m - nm);
#pragma unroll
        for (int r = 0; r < 16; ++r) { acc0[r] *= al; acc1[r] *= al; }
        ll *= al;
        m = nm;
      }
      f32x16 p;
#pragma unroll
      for (int r = 0; r < 16; ++r) p[r] = exp2f(s[r] - m);
      float rs = 0.f;
#pragma unroll
      for (int r = 0; r < 16; ++r) rs += p[r];
      ll += xhalf_sum(rs);
      uint32_t a0 = cvtpk_bf16(p[0], p[1]),   b0 = cvtpk_bf16(p[2], p[3]);
      uint32_t c0 = cvtpk_bf16(p[4], p[5]),   d0 = cvtpk_bf16(p[6], p[7]);
      uint32_t a1 = cvtpk_bf16(p[8], p[9]),   b1 = cvtpk_bf16(p[10], p[11]);
      uint32_t c1 = cvtpk_bf16(p[12], p[13]), d1 = cvtpk_bf16(p[14], p[15]);
      auto r0 = __builtin_amdgcn_permlane32_swap(a0, c0, false, false);
      auto r1 = __builtin_amdgcn_permlane32_swap(b0, d0, false, false);
      auto r2 = __builtin_amdgcn_permlane32_swap(a1, c1, false, false);
      auto r3 = __builtin_amdgcn_permlane32_swap(b1, d1, false, false);
      union { uint32_t w[4]; bf16x8 v; } pf0u, pf1u;
      pf0u.w[0] = r0[0]; pf0u.w[1] = r1[0]; pf0u.w[2] = r0[1]; pf0u.w[3] = r1[1];
      pf1u.w[0] = r2[0]; pf1u.w[1] = r3[0]; pf1u.w[2] = r2[1]; pf1u.w[3] = r3[1];
      acc0 = __builtin_amdgcn_mfma_f32_32x32x16_bf16(vc00, pf0u.v, acc0, 0, 0, 0);
      acc0 = __builtin_amdgcn_mfma_f32_32x32x16_bf16(vc01, pf1u.v, acc0, 0, 0, 0);
      acc1 = __builtin_amdgcn_mfma_f32_32x32x16_bf16(vc10, pf0u.v, acc1, 0, 0, 0);
      acc1 = __builtin_amdgcn_mfma_f32_32x32x16_bf16(vc11, pf1u.v, acc1, 0, 0, 0);
      kc0 = kn0; kc1 = kn1; kc2 = kn2; kc3 = kn3;
      vc00 = vn00; vc01 = vn01; vc10 = vn10; vc11 = vn11;
      wcur = wnext;
    }
  }
  // ---- stash per-wave state in LDS (raw acc + m,l) ----
  if (hi == 0) mlS[w * 32 + l31] = make_float2(m, ll);
  float* wbase = accS + w * 2048 + (l31 << 6);
  const int sw = (l31 & 15) << 2;  // swizzle: d ^= sw
#pragma unroll
  for (int t = 0; t < 4; ++t) {
    int dA = (8 * t + 4 * hi) ^ sw;
    int dB = (32 + 8 * t + 4 * hi) ^ sw;
    float4 v0 = {acc0[4 * t], acc0[4 * t + 1], acc0[4 * t + 2], acc0[4 * t + 3]};
    float4 v1 = {acc1[4 * t], acc1[4 * t + 1], acc1[4 * t + 2], acc1[4 * t + 3]};
    *(float4*)(wbase + dA) = v0;
    *(float4*)(wbase + dB) = v1;
  }
  __syncthreads();
  // ---- combine: thread -> (q = tid&31, d = (tid>>5)*8) ----
  const int q = threadIdx.x & 31;
  const int dd = (threadIdx.x >> 5) * 8;
  float2 ml0 = mlS[q], ml1 = mlS[32 + q], ml2 = mlS[64 + q], ml3 = mlS[96 + q];
  float M = fmaxf(fmaxf(ml0.x, ml1.x), fmaxf(ml2.x, ml3.x));
  float w0 = exp2f(ml0.x - M), w1 = exp2f(ml1.x - M);
  float w2 = exp2f(ml2.x - M), w3 = exp2f(ml3.x - M);
  float L = ml0.y * w0 + ml1.y * w1 + ml2.y * w2 + ml3.y * w3;
  const int offA = (q << 6) + (dd ^ ((q & 15) << 2));
  const int offB = offA ^ 4;
  float o[8];
  {
    float4 xa = *(float4*)(accS + offA);
    float4 xb = *(float4*)(accS + offB);
    o[0] = w0 * xa.x; o[1] = w0 * xa.y; o[2] = w0 * xa.z; o[3] = w0 * xa.w;
    o[4] = w0 * xb.x; o[5] = w0 * xb.y; o[6] = w0 * xb.z; o[7] = w0 * xb.w;
  }
  {
    float4 xa = *(float4*)(accS + 2048 + offA);
    float4 xb = *(float4*)(accS + 2048 + offB);
    o[0] += w1 * xa.x; o[1] += w1 * xa.y; o[2] += w1 * xa.z; o[3] += w1 * xa.w;
    o[4] += w1 * xb.x; o[5] += w1 * xb.y; o[6] += w1 * xb.z; o[7] += w1 * xb.w;
  }
  {
    float4 xa = *(float4*)(accS + 4096 + offA);
    float4 xb = *(float4*)(accS + 4096 + offB);
    o[0] += w2 * xa.x; o[1] += w2 * xa.y; o[2] += w2 * xa.z; o[3] += w2 * xa.w;
    o[4] += w2 * xb.x; o[5] += w2 * xb.y; o[6] += w2 * xb.z; o[7] += w2 * xb.w;
  }
  {
    float4 xa = *(float4*)(accS + 6144 + offA);
    float4 xb = *(float4*)(accS + 6144 + offB);
    o[0] += w3 * xa.x; o[1] += w3 * xa.y; o[2] += w3 * xa.z; o[3] += w3 * xa.w;
    o[4] += w3 * xb.x; o[5] += w3 * xb.y; o[6] += w3 * xb.z; o[7] += w3 * xb.w;
  }
  const float invL = 1.0f / L;
  uint4 pk;
  pk.x = cvtpk_bf16(o[0] * invL, o[1] * invL);
  pk.y = cvtpk_bf16(o[2] * invL, o[3] * invL);
  pk.z = cvtpk_bf16(o[4] * invL, o[5] * invL);
  pk.w = cvtpk_bf16(o[6] * invL, o[7] * invL);
  *(uint4*)(Aout + (size_t)(q0 + q) * HIDDEN + h * 64 + dd) = pk;
}

// ---------------- launch ----------------

extern "C" void kernel_launch(void* const* d_in, const int* in_sizes, int n_in,
                              void* d_out, int out_size, void* d_ws, size_t ws_size,
                              hipStream_t stream) {
  const float* hidden  = (const float*)d_in[0];
  const float* webmask = (const float*)d_in[3];
  const float* Wq = (const float*)d_in[4];
  const float* Wk = (const float*)d_in[5];
  const float* Wv = (const float*)d_in[6];
  const float* Wo = (const float*)d_in[7];
  const float* qlnw = (const float*)d_in[8];
  const float* klnw = (const float*)d_in[9];
  float* out = (float*)d_out;

  char* ws = (char*)d_ws;
  u16*      hbf  = (u16*)(ws);                         // 8 MB  hidden bf16
  u16*      Wcat = (u16*)(ws + (8u << 20));            // 12 MB QKV weights^T
  u16*      Wot  = (u16*)(ws + (20u << 20));           // 8 MB  Wo^T
  float*    qkv  = (float*)(ws + (28u << 20));         // 24 MB QKV fp32
  u16*      Qh   = (u16*)(ws + (52u << 20));           // 8 MB  Q' (pre-scaled)
  u16*      Kh   = (u16*)(ws + (60u << 20));           // 2 MB  K'
  u16*      Vt   = (u16*)(ws + (62u << 20));           // 2 MB  V^T
  u16*      Ao   = (u16*)(ws + (64u << 20));           // 8 MB  attn out bf16
  uint32_t* mb   = (uint32_t*)(ws + (72u << 20));      // 0.5 MB web mask bits

  prep_all<<<14848, 256, 0, stream>>>(hidden, hbf, Wq, Wk, Wv, Wo, Wcat, Wot,
                                      webmask, mb);
  gemm_tn<<<768, 256, 0, stream>>>(hbf, Wcat, qkv, SLEN, QKVN, HIDDEN);
  rope_vtrans<<<20992, 256, 0, stream>>>(qkv, qlnw, klnw, Qh, Kh, Vt);
  attn_fused<<<1024, 256, 0, stream>>>(Qh, Kh, Vt, mb, Ao, 0);
  attn_fused<<<1024, 256, 0, stream>>>(Qh, Kh, Vt, mb, Ao, 16);
  gemm_tn<<<512, 256, 0, stream>>>(Ao, Wot, out, SLEN, HIDDEN, HIDDEN);
}